// Round 13
// baseline (414.631 us; speedup 1.0000x reference)
//
#include <hip/hip_runtime.h>
#include <hip/hip_bf16.h>
#include <cstdint>
#include <cstddef>

// ---------------------------------------------------------------------------
// Transformer block: LN1 -> MHA(16 heads, no mask) -> +res -> LN2 -> GELU MLP -> +res
// B=8 T=1024 D=1024 H=16 HD=64 FF=4096.  bf16 MFMA everywhere, fp32 accum.
// ---------------------------------------------------------------------------

typedef __bf16 bf16;
typedef __bf16 bf16x8 __attribute__((ext_vector_type(8)));
typedef __bf16 bf16x4 __attribute__((ext_vector_type(4)));
typedef float  f32x4  __attribute__((ext_vector_type(4)));
typedef uint32_t u32x4 __attribute__((ext_vector_type(4)));

#define BB    8
#define TT    1024
#define DD    1024
#define HH    16
#define HDIM  64
#define FFD   4096
#define MROWS (BB*TT)   // 8192

// async global->LDS, 16B per lane, LDS dest = wave-uniform base + lane*16
__device__ __forceinline__ void async_ld16(const void* g, void* l) {
  __builtin_amdgcn_global_load_lds(
      (const __attribute__((address_space(1))) uint32_t*)g,
      (__attribute__((address_space(3))) uint32_t*)l, 16, 0, 0);
}

// cheap GELU (tanh form, |err vs erf-form| <~1e-3, absorbed by bf16 out)
__device__ __forceinline__ float gelu_f(float v) {
  float z = 0.7978845608028654f * (v + 0.044715f * v * v * v);
  z = fminf(fmaxf(z, -9.0f), 9.0f);
  const float e = __expf(-2.0f * z);
  const float th = 1.0f - __fdividef(2.0f * e, 1.0f + e);
  return 0.5f * v * (1.0f + th);
}

// raw v_exp_f32: 2^x
__device__ __forceinline__ float exp2_fast(float x) {
  float r; asm("v_exp_f32 %0, %1" : "=v"(r) : "v"(x)); return r;
}
// packed f32->bf16 pair (no builtin on gfx950)
__device__ __forceinline__ uint32_t cvt_pk_bf16(float a, float b) {
  uint32_t r; asm("v_cvt_pk_bf16_f32 %0, %1, %2" : "=v"(r) : "v"(a), "v"(b));
  return r;
}

// ---------------------------------------------------------------------------
// Weight repack: src (K,N) f32 row-major -> dst (N,K) bf16 row-major (B^T)
// ---------------------------------------------------------------------------
__global__ void k_transpose_cast(const float* __restrict__ src, bf16* __restrict__ dst,
                                 int K, int N) {
  __shared__ float tile[32][33];
  const size_t boff = (size_t)blockIdx.z * K * N;
  src += boff; dst += boff;
  const int k0 = blockIdx.y * 32, n0 = blockIdx.x * 32;
  const int tx = threadIdx.x, ty = threadIdx.y; // (32,8)
#pragma unroll
  for (int i = 0; i < 4; ++i)
    tile[ty + i*8][tx] = src[(size_t)(k0 + ty + i*8) * N + n0 + tx];
  __syncthreads();
#pragma unroll
  for (int i = 0; i < 4; ++i)
    dst[(size_t)(n0 + ty + i*8) * K + k0 + tx] = (bf16)tile[tx][ty + i*8];
}

__global__ void k_concat_bias(const float* __restrict__ bq, const float* __restrict__ bk,
                              const float* __restrict__ bv, float* __restrict__ out) {
  int i = blockIdx.x * 256 + threadIdx.x; // 3072
  float v = (i < 1024) ? bq[i] : (i < 2048) ? bk[i - 1024] : bv[i - 2048];
  out[i] = v;
}

// V part of qkv (B*T, 3072) -> vT[b][h][e][t]
__global__ void k_transpose_v(const bf16* __restrict__ qkv, bf16* __restrict__ vT) {
  __shared__ bf16 tile[32][33];
  const int bh = blockIdx.z;
  const int b = bh >> 4, h = bh & 15;
  const int t0 = blockIdx.x * 32, e0 = blockIdx.y * 32;
  const int tx = threadIdx.x, ty = threadIdx.y; // (32,8)
  const bf16* src = qkv + (size_t)b * TT * 3072 + 2048 + h * 64;
#pragma unroll
  for (int i = 0; i < 4; ++i)
    tile[ty + i*8][tx] = src[(size_t)(t0 + ty + i*8) * 3072 + e0 + tx];
  __syncthreads();
  bf16* dst = vT + ((size_t)bh * 64 + e0) * TT + t0;
#pragma unroll
  for (int i = 0; i < 4; ++i)
    dst[(size_t)(ty + i*8) * TT + tx] = tile[tx][ty + i*8];
}

// ---------------------------------------------------------------------------
// LayerNorm: one block per row (D=1024), 256 threads, f32 in -> bf16 out
// ---------------------------------------------------------------------------
__global__ void k_layernorm(const float* __restrict__ x, const float* __restrict__ g,
                            const float* __restrict__ b, bf16* __restrict__ out) {
  const int row = blockIdx.x, tid = threadIdx.x;
  const float* xr = x + (size_t)row * DD;
  f32x4 v = *(const f32x4*)(xr + tid * 4);
  float s  = v[0] + v[1] + v[2] + v[3];
  float ss = v[0]*v[0] + v[1]*v[1] + v[2]*v[2] + v[3]*v[3];
#pragma unroll
  for (int m = 1; m < 64; m <<= 1) { s += __shfl_xor(s, m); ss += __shfl_xor(ss, m); }
  __shared__ float red[8];
  const int wid = tid >> 6;
  if ((tid & 63) == 0) { red[wid*2] = s; red[wid*2+1] = ss; }
  __syncthreads();
  s  = red[0] + red[2] + red[4] + red[6];
  ss = red[1] + red[3] + red[5] + red[7];
  const float mu = s * (1.0f / DD);
  const float var = ss * (1.0f / DD) - mu * mu;
  const float rs = rsqrtf(var + 1e-5f);
  bf16x4 o;
#pragma unroll
  for (int j = 0; j < 4; ++j)
    o[j] = (bf16)((v[j] - mu) * rs * g[tid*4 + j] + b[tid*4 + j]);
  *(bf16x4*)&out[(size_t)row * DD + tid * 4] = o;
}

// ---------------------------------------------------------------------------
// Shared helper macros for 256-tile 8-wave GEMMs
// ---------------------------------------------------------------------------
#define RD_B(reg, base) { _Pragma("unroll") \
    for (int nf = 0; nf < 4; ++nf) reg[nf] = *(const bf16x8*)((base) + nf*1024); }
#define RD_A4(reg, base, mb) { _Pragma("unroll") \
    for (int mf = 0; mf < 4; ++mf) reg[mf] = *(const bf16x8*)((base) + (mb+mf)*1024); }
#define MM(areg, breg, mb) { _Pragma("unroll") \
    for (int mf = 0; mf < 4; ++mf) _Pragma("unroll") \
      for (int nf = 0; nf < 4; ++nf) \
        acc[mb+mf][nf] = __builtin_amdgcn_mfma_f32_16x16x32_bf16(areg[mf], breg[nf], acc[mb+mf][nf], 0, 0, 0); }
#define SGA(off, lb) { async_ld16(aG0 + (off), (lb)+0*64);   async_ld16(aG1 + (off), (lb)+64*64); \
                       async_ld16(aG2 + (off), (lb)+128*64); async_ld16(aG3 + (off), (lb)+192*64); }
// half-tile stages (2 loads each)
#define SGA_S0(off, lb) { async_ld16(aG0 + (off), (lb)+0*64);    async_ld16(aG2 + (off), (lb)+128*64); }
#define SGA_S1(off, lb) { async_ld16(aG1 + (off), (lb)+64*64);   async_ld16(aG3 + (off), (lb)+192*64); }
#define SGB_Q0(off, lb) { async_ld16(bG0 + (off), (lb)+0*64);    async_ld16(bG1 + (off), (lb)+64*64); }
#define SGB_Q1(off, lb) { async_ld16(bG2 + (off), (lb)+128*64);  async_ld16(bG3 + (off), (lb)+192*64); }
#define WAIT_LGKM { asm volatile("s_waitcnt lgkmcnt(0)" ::: "memory"); __builtin_amdgcn_sched_barrier(0); }
#define VMC(n)  { asm volatile("s_waitcnt vmcnt(" #n ")" ::: "memory"); __builtin_amdgcn_sched_barrier(0); }
#define BAR __builtin_amdgcn_s_barrier()
#define PR1 __builtin_amdgcn_s_setprio(1)
#define PR0 __builtin_amdgcn_s_setprio(0)

// ---------------------------------------------------------------------------
// k_gemm256n: 256x128 tile, 8 waves (4x2), BK=64, LDS 96 KB.
// Fixes grid quantization for N%256!=0-friendly shapes (QKV: 768 blocks = 3/CU
// exact vs 384 = 1.5/CU at 256x256). 2 phases/tile {8 ds_read; bar; lgkm0;
// 16 MFMA; bar}; full tile t+2 (6 loads) staged after last-reader barrier;
// boundary vmcnt(6) (queue [t+1:6, t+2:6] -> drain t+1, t+2 flies ~2 phases).
// MODE 0: bf16 bias | MODE 1: bf16 gelu(bias)
// ---------------------------------------------------------------------------
template<int MODE>
__global__ __launch_bounds__(512, 2)
void k_gemm256n(const bf16* __restrict__ A, const bf16* __restrict__ Bt,
                const float* __restrict__ bias, bf16* __restrict__ outb,
                int M, int N, int K) {
  __shared__ __align__(16) bf16 As[2][256 * 64];   // 64 KB
  __shared__ __align__(16) bf16 Bs[2][128 * 64];   // 32 KB
  const int tid = threadIdx.x;
  const int w = tid >> 6, l = tid & 63;
  const int wm = w >> 1, wn = w & 1;               // 4 x 2 waves
  const int l15 = l & 15, l4 = l >> 4;
  const int nbx = N >> 7;                          // 128-wide column tiles
  const int nwg = gridDim.x;
  const int cpx = nwg >> 3;
  const int swz = (blockIdx.x & 7) * cpx + (blockIdx.x >> 3);
  const int m0 = (swz / nbx) << 8, n0 = (swz % nbx) << 7;
  f32x4 acc[4][4] = {};
  const int l7 = l15 & 7;
  const int c0 = (l4 ^ l7) * 8;
  const int c1 = ((4 + l4) ^ l7) * 8;
  const bf16* const A00 = &As[0][(wm*64 + l15)*64 + c0];
  const bf16* const A01 = &As[0][(wm*64 + l15)*64 + c1];
  const bf16* const A10 = &As[1][(wm*64 + l15)*64 + c0];
  const bf16* const A11 = &As[1][(wm*64 + l15)*64 + c1];
  const bf16* const B00 = &Bs[0][(wn*64 + l15)*64 + c0];
  const bf16* const B01 = &Bs[0][(wn*64 + l15)*64 + c1];
  const bf16* const B10 = &Bs[1][(wn*64 + l15)*64 + c0];
  const bf16* const B11 = &Bs[1][(wn*64 + l15)*64 + c1];
  const int srow = l >> 3, sch = l & 7;
  const int schx = (sch ^ srow) * 8;
  const bf16* const aG0 = A  + (size_t)(m0 + w*8 + srow) * K + schx;
  const bf16* const aG1 = aG0 + (size_t)64 * K;
  const bf16* const aG2 = aG0 + (size_t)128 * K;
  const bf16* const aG3 = aG0 + (size_t)192 * K;
  const bf16* const bG0 = Bt + (size_t)(n0 + w*8 + srow) * K + schx;
  const bf16* const bG1 = bG0 + (size_t)64 * K;
  bf16* const LA0 = (bf16*)As[0] + w*512;
  bf16* const LA1 = (bf16*)As[1] + w*512;
  bf16* const LB0 = (bf16*)Bs[0] + w*512;
  bf16* const LB1 = (bf16*)Bs[1] + w*512;
  const int NT = K >> 6;   // even

#define SGB2(off, lb) { async_ld16(bG0 + (off), (lb)+0*64); async_ld16(bG1 + (off), (lb)+64*64); }

  // prologue: tile0 -> buf0 (6), tile1 -> buf1 (6); drain tile0
  SGA(0, LA0)  SGB2(0, LB0)
  SGA(64, LA1) SGB2(64, LB1)
  VMC(6);
  BAR;

  size_t ko = 0;
  for (int T = 0; T < NT; T += 2) {
    const bool nl  = (T + 2 < NT);
    const bool nl2 = (T + 3 < NT);
    bf16x8 b0[4], b1[4], a[4], a2[4];

    // ===== tile T (buf0) =====
    RD_B(b0, B00) RD_A4(a, A00, 0)
    BAR; WAIT_LGKM;
    PR1; MM(a, b0, 0) PR0;
    BAR;
    RD_B(b1, B01) RD_A4(a2, A01, 0)
    BAR; WAIT_LGKM;
    PR1; MM(a2, b1, 0) PR0;
    BAR;                                   // all buf0 reads drained on ALL waves
    if (nl) { SGA(ko + 128, LA0) SGB2(ko + 128, LB0) }   // tile T+2 -> buf0
    if (nl) { VMC(6); } else { VMC(0); }   // t+1 landed; t+2 in flight
    BAR;

    // ===== tile T+1 (buf1) =====
    RD_B(b0, B10) RD_A4(a, A10, 0)
    BAR; WAIT_LGKM;
    PR1; MM(a, b0, 0) PR0;
    BAR;
    RD_B(b1, B11) RD_A4(a2, A11, 0)
    BAR; WAIT_LGKM;
    PR1; MM(a2, b1, 0) PR0;
    BAR;                                   // all buf1 reads drained
    if (nl2) { SGA(ko + 192, LA1) SGB2(ko + 192, LB1) }  // tile T+3 -> buf1
    if (nl2) { VMC(6); } else { VMC(0); }
    BAR;

    ko += 128;
  }
#undef SGB2

  // epilogue
#pragma unroll
  for (int mf = 0; mf < 4; ++mf) {
#pragma unroll
    for (int r = 0; r < 4; ++r) {
      const size_t grow = (size_t)(m0 + wm*64 + mf*16 + l4*4 + r);
      const size_t rowoff = grow * (size_t)N;
#pragma unroll
      for (int nf = 0; nf < 4; ++nf) {
        const int gcol = n0 + wn*64 + nf*16 + l15;
        float v = acc[mf][nf][r] + bias[gcol];
        if constexpr (MODE == 1) v = gelu_f(v);
        outb[rowoff + gcol] = (bf16)v;
      }
    }
  }
}

// ---------------------------------------------------------------------------
// k_gemm256p: 256x256 per-phase interleave (R12, 101.5 us at FF1). FF1 kernel.
// ---------------------------------------------------------------------------
template<int MODE>
__global__ __launch_bounds__(512, 2)
void k_gemm256p(const bf16* __restrict__ A, const bf16* __restrict__ Bt,
                const float* __restrict__ bias, bf16* __restrict__ outb,
                int M, int N, int K) {
  __shared__ __align__(16) bf16 As[2][256 * 64];
  __shared__ __align__(16) bf16 Bs[2][256 * 64];
  const int tid = threadIdx.x;
  const int w = tid >> 6, l = tid & 63;
  const int wm = w >> 2, wn = w & 3;
  const int l15 = l & 15, l4 = l >> 4;
  const int nbx = N >> 8;
  const int nwg = gridDim.x;
  const int cpx = nwg >> 3;
  const int swz = (blockIdx.x & 7) * cpx + (blockIdx.x >> 3);
  const int m0 = (swz / nbx) << 8, n0 = (swz % nbx) << 8;
  f32x4 acc[8][4] = {};
  const int l7 = l15 & 7;
  const int c0 = (l4 ^ l7) * 8;
  const int c1 = ((4 + l4) ^ l7) * 8;
  const bf16* const A00 = &As[0][(wm*128 + l15)*64 + c0];
  const bf16* const A01 = &As[0][(wm*128 + l15)*64 + c1];
  const bf16* const A10 = &As[1][(wm*128 + l15)*64 + c0];
  const bf16* const A11 = &As[1][(wm*128 + l15)*64 + c1];
  const bf16* const B00 = &Bs[0][(wn*64 + l15)*64 + c0];
  const bf16* const B01 = &Bs[0][(wn*64 + l15)*64 + c1];
  const bf16* const B10 = &Bs[1][(wn*64 + l15)*64 + c0];
  const bf16* const B11 = &Bs[1][(wn*64 + l15)*64 + c1];
  const int srow = l >> 3, sch = l & 7;
  const int schx = (sch ^ srow) * 8;
  const bf16* const aG0 = A  + (size_t)(m0 + w*8 + srow) * K + schx;
  const bf16* const aG1 = aG0 + (size_t)64 * K;
  const bf16* const aG2 = aG0 + (size_t)128 * K;
  const bf16* const aG3 = aG0 + (size_t)192 * K;
  const bf16* const bG0 = Bt + (size_t)(n0 + w*8 + srow) * K + schx;
  const bf16* const bG1 = bG0 + (size_t)64 * K;
  const bf16* const bG2 = bG0 + (size_t)128 * K;
  const bf16* const bG3 = bG0 + (size_t)192 * K;
  bf16* const LA0 = (bf16*)As[0] + w*512;
  bf16* const LA1 = (bf16*)As[1] + w*512;
  bf16* const LB0 = (bf16*)Bs[0] + w*512;
  bf16* const LB1 = (bf16*)Bs[1] + w*512;
  const int NT = K >> 6;

  // prologue: A(0)+B(0) -> buf0 (8 loads), Ah0(1) -> buf1 (2 loads)
  SGA_S0(0, LA0) SGA_S1(0, LA0)
  SGB_Q0(0, LB0) SGB_Q1(0, LB0)
  SGA_S0(64, LA1)
  VMC(2);
  BAR;

  size_t ko = 0;
  for (int T = 0; T < NT; T += 2) {
    const bool s2 = (T + 2 < NT);
    const bool s3 = (T + 3 < NT);
    bf16x8 b0[4], b1[4], a[4];

    // ===== tile T (buf0) =====
    RD_B(b0, B00) RD_A4(a, A00, 0)
    SGA_S1(ko + 64, LA1)
    BAR; WAIT_LGKM;
    PR1; MM(a, b0, 0) PR0;
    BAR;
    RD_B(b1, B01) RD_A4(a, A01, 0)
    SGB_Q0(ko + 64, LB1)
    BAR; WAIT_LGKM;
    PR1; MM(a, b1, 0) PR0;
    BAR;
    RD_A4(a, A00, 4)
    SGB_Q1(ko + 64, LB1)
    BAR; WAIT_LGKM;
    PR1; MM(a, b0, 4) PR0;
    BAR;
    RD_A4(a, A01, 4)
    if (s2) SGA_S0(ko + 128, LA0)
    BAR; WAIT_LGKM;
    PR1; MM(a, b1, 4) PR0;
    if (s2) { VMC(2); } else { VMC(0); }
    BAR;

    // ===== tile T+1 (buf1) =====
    RD_B(b0, B10) RD_A4(a, A10, 0)
    if (s2) SGA_S1(ko + 128, LA0)
    BAR; WAIT_LGKM;
    PR1; MM(a, b0, 0) PR0;
    BAR;
    RD_B(b1, B11) RD_A4(a, A11, 0)
    if (s2) SGB_Q0(ko + 128, LB0)
    BAR; WAIT_LGKM;
    PR1; MM(a, b1, 0) PR0;
    BAR;
    RD_A4(a, A10, 4)
    if (s2) SGB_Q1(ko + 128, LB0)
    BAR; WAIT_LGKM;
    PR1; MM(a, b0, 4) PR0;
    BAR;
    RD_A4(a, A11, 4)
    if (s3) SGA_S0(ko + 192, LA1)
    BAR; WAIT_LGKM;
    PR1; MM(a, b1, 4) PR0;
    if (s3) { VMC(2); } else { VMC(0); }
    BAR;

    ko += 128;
  }

  // epilogue
#pragma unroll
  for (int mf = 0; mf < 8; ++mf) {
#pragma unroll
    for (int r = 0; r < 4; ++r) {
      const size_t grow = (size_t)(m0 + wm*128 + mf*16 + l4*4 + r);
      const size_t rowoff = grow * (size_t)N;
#pragma unroll
      for (int nf = 0; nf < 4; ++nf) {
        const int gcol = n0 + wn*64 + nf*16 + l15;
        float v = acc[mf][nf][r] + bias[gcol];
        if constexpr (MODE == 1) v = gelu_f(v);
        outb[rowoff + gcol] = (bf16)v;
      }
    }
  }
}

// ---------------------------------------------------------------------------
// GEMM 128x128 (Wo: N=1024 K=1024, FF2: N=1024 K=4096). MODE 2: f32 bias+res.
// ---------------------------------------------------------------------------
template<int MODE>
__global__ __launch_bounds__(256)
void k_gemm(const bf16* __restrict__ A, const bf16* __restrict__ Bt,
            const float* __restrict__ bias, const float* __restrict__ res,
            bf16* __restrict__ outb, float* __restrict__ outf,
            int M, int N, int K) {
  __shared__ __align__(16) bf16 As[128 * 64];
  __shared__ __align__(16) bf16 Bs[128 * 64];
  const int tid = threadIdx.x;
  const int w = tid >> 6, l = tid & 63;
  const int wm = w >> 1, wn = w & 1;
  const int l15 = l & 15, l4 = l >> 4;
  const int m0 = blockIdx.y * 128, n0 = blockIdx.x * 128;

  f32x4 acc[4][4] = {};

  const int l7 = l15 & 7;
  const int c0 = (l4 ^ l7) * 8, c1 = ((4 + l4) ^ l7) * 8;
  const bf16* const Ab = &As[(wm*64 + l15)*64];
  const bf16* const Bb = &Bs[(wn*64 + l15)*64];

  const int sr8 = l >> 3, sl7 = l & 7;
  const int schx = (sl7 ^ sr8) * 8;
  const bf16* const gA0 = A  + (size_t)(m0 + w*32 + sr8) * K + schx;
  const bf16* const gA1 = gA0 + (size_t)8 * K;
  const bf16* const gA2 = gA0 + (size_t)16 * K;
  const bf16* const gA3 = gA0 + (size_t)24 * K;
  const bf16* const gB0 = Bt + (size_t)(n0 + w*32 + sr8) * K + schx;
  const bf16* const gB1 = gB0 + (size_t)8 * K;
  const bf16* const gB2 = gB0 + (size_t)16 * K;
  const bf16* const gB3 = gB0 + (size_t)24 * K;
  bf16* const lA = (bf16*)As + w*32*64;
  bf16* const lB = (bf16*)Bs + w*32*64;

  for (int k0 = 0; k0 < K; k0 += 64) {
    async_ld16(gA0 + k0, lA);          async_ld16(gA1 + k0, lA + 8*64);
    async_ld16(gA2 + k0, lA + 16*64);  async_ld16(gA3 + k0, lA + 24*64);
    async_ld16(gB0 + k0, lB);          async_ld16(gB1 + k0, lB + 8*64);
    async_ld16(gB2 + k0, lB + 16*64);  async_ld16(gB3 + k0, lB + 24*64);
    __syncthreads();
#pragma unroll
    for (int kk = 0; kk < 2; ++kk) {
      const int cc = kk ? c1 : c0;
      bf16x8 af[4], bfr[4];
#pragma unroll
      for (int mf = 0; mf < 4; ++mf) af[mf] = *(const bf16x8*)(Ab + mf*1024 + cc);
#pragma unroll
      for (int nf = 0; nf < 4; ++nf) bfr[nf] = *(const bf16x8*)(Bb + nf*1024 + cc);
#pragma unroll
      for (int mf = 0; mf < 4; ++mf)
#pragma unroll
        for (int nf = 0; nf < 4; ++nf)
          acc[mf][nf] = __builtin_amdgcn_mfma_f32_16x16x32_bf16(af[mf], bfr[nf], acc[mf][nf], 0, 0, 0);
    }
    __syncthreads();
  }

#pragma unroll
  for (int mf = 0; mf < 4; ++mf) {
#pragma unroll
    for (int r = 0; r < 4; ++r) {
      const size_t grow = (size_t)(m0 + wm*64 + mf*16 + l4*4 + r);
      const size_t rowoff = grow * (size_t)N;
#pragma unroll
      for (int nf = 0; nf < 4; ++nf) {
        const int gcol = n0 + wn*64 + nf*16 + l15;
        float v = acc[mf][nf][r] + bias[gcol];
        if constexpr (MODE == 1) v = gelu_f(v);
        if constexpr (MODE == 2) {
          v += res[rowoff + gcol];
          outf[rowoff + gcol] = v;
        } else {
          outb[rowoff + gcol] = (bf16)v;
        }
      }
    }
  }
}

// ---------------------------------------------------------------------------
// Flash attention v4 (R7, unchanged): swapped QK^T (lane owns q=l15),
// in-register P via cvt_pk + ds_bpermute; 512 thr = 8 waves x 16 q-rows;
// KV tiles 64, dbuf swizzled LDS (32 KB); XCD-chunked grid; defer-max.
// ---------------------------------------------------------------------------
__global__ __launch_bounds__(512)
void k_attn(const bf16* __restrict__ qkv, const bf16* __restrict__ vT,
            bf16* __restrict__ ctx) {
  const int tid = threadIdx.x;
  const int w = tid >> 6, l = tid & 63;
  const int l15 = l & 15, l4 = l >> 4;

  const int gid = ((int)blockIdx.x & 7) * 128 + ((int)blockIdx.x >> 3);
  const int qt = gid & 7;
  const int bh = gid >> 3;
  const int h = bh & 15, b = bh >> 4;

  __shared__ __align__(16) bf16 Ks[2][64 * 64];
  __shared__ __align__(16) bf16 Vs[2][64 * 64];

  const bf16* base = qkv + (size_t)b * TT * 3072;
  const bf16* Qp = base + h * 64;
  const bf16* Kp = base + 1024 + h * 64;
  const bf16* Vtp = vT + (size_t)bh * HDIM * TT;

  const float SCL = 0.125f * 1.44269504f;
  const float THR = 8.0f * 1.44269504f;

  const int qrow = qt * 128 + w * 16 + l15;
  bf16x8 qf[2];
  {
    bf16x8 q0 = *(const bf16x8*)&Qp[(size_t)qrow * 3072 + l4 * 8];
    bf16x8 q1 = *(const bf16x8*)&Qp[(size_t)qrow * 3072 + 32 + l4 * 8];
#pragma unroll
    for (int j = 0; j < 8; ++j) {
      qf[0][j] = (bf16)((float)q0[j] * SCL);
      qf[1][j] = (bf16)((float)q1[j] * SCL);
    }
  }

  f32x4 oacc[4] = {};
  float mrow = -1e30f;
  float lrow = 0.f;

  const int l7 = l15 & 7;
  const int c0 = (l4 ^ l7) * 8, c1 = ((4 + l4) ^ l7) * 8;

  const int aL0 = (((l4 & 1) << 5) + l15) << 2;
  const int aL1 = aL0 + 64;
  const bool hi = (l & 32) != 0;

  const int srow = w * 8 + (l >> 3);
  const int sch = (l & 7) ^ (srow & 7);

  auto stage = [&](int buf, int t) {
    const int kv0 = t * 64;
    async_ld16(Kp + (size_t)(kv0 + srow) * 3072 + sch * 8, &Ks[buf][w * 512]);
    async_ld16(Vtp + (size_t)srow * TT + kv0 + sch * 8, &Vs[buf][w * 512]);
  };

  stage(0, 0);
  for (int t = 0; t < TT / 64; ++t) {
    const int cur = t & 1;
    __syncthreads();
    if (t + 1 < TT / 64) stage(cur ^ 1, t + 1);

    const bf16* const Kc = &Ks[cur][l15 * 64];
    const bf16* const Vc = &Vs[cur][l15 * 64];

    f32x4 sacc[4] = {};
    __builtin_amdgcn_s_setprio(1);
#pragma unroll
    for (int nf = 0; nf < 4; ++nf) {
      bf16x8 k0 = *(const bf16x8*)(Kc + nf*1024 + c0);
      bf16x8 k1 = *(const bf16x8*)(Kc + nf*1024 + c1);
      sacc[nf] = __builtin_amdgcn_mfma_f32_16x16x32_bf16(k0, qf[0], sacc[nf], 0, 0, 0);
      sacc[nf] = __builtin_amdgcn_mfma_f32_16x16x32_bf16(k1, qf[1], sacc[nf], 0, 0, 0);
    }
    __builtin_amdgcn_s_setprio(0);

    float m = fmaxf(fmaxf(sacc[0][0], sacc[0][1]), fmaxf(sacc[0][2], sacc[0][3]));
#pragma unroll
    for (int nf = 1; nf < 4; ++nf)
      m = fmaxf(m, fmaxf(fmaxf(sacc[nf][0], sacc[nf][1]), fmaxf(sacc[nf][2], sacc[nf][3])));
    m = fmaxf(m, __shfl_xor(m, 16));
    m = fmaxf(m, __shfl_xor(m, 32));

    const int ok = (m <= mrow + THR);
    if (!__all(ok)) {
      const float mn = fmaxf(mrow, m);
      const float e = exp2_fast(mrow - mn);
      mrow = mn;
      lrow *= e;
      const int qb = l4 << 2;
      float e0 = __shfl(e, qb + 0), e1 = __shfl(e, qb + 1);
      float e2 = __shfl(e, qb + 2), e3 = __shfl(e, qb + 3);
#pragma unroll
      for (int nf = 0; nf < 4; ++nf) {
        oacc[nf][0] *= e0; oacc[nf][1] *= e1;
        oacc[nf][2] *= e2; oacc[nf][3] *= e3;
      }
    }

    float p[4][4];
    float ls = 0.f;
    uint32_t pk0[4], pk1[4];
#pragma unroll
    for (int nf = 0; nf < 4; ++nf) {
#pragma unroll
      for (int r = 0; r < 4; ++r) {
        p[nf][r] = exp2_fast(sacc[nf][r] - mrow);
        ls += p[nf][r];
      }
      pk0[nf] = cvt_pk_bf16(p[nf][0], p[nf][1]);
      pk1[nf] = cvt_pk_bf16(p[nf][2], p[nf][3]);
    }
    ls += __shfl_xor(ls, 16);
    ls += __shfl_xor(ls, 32);
    lrow += ls;

    __builtin_amdgcn_s_setprio(1);
#pragma unroll
    for (int kk = 0; kk < 2; ++kk) {
      const int nfa = 2*kk, nfb = 2*kk + 1;
      int u0 = __builtin_amdgcn_ds_bpermute(aL0, (int)pk0[nfa]);
      int u1 = __builtin_amdgcn_ds_bpermute(aL0, (int)pk0[nfb]);
      int v0 = __builtin_amdgcn_ds_bpermute(aL0, (int)pk1[nfa]);
      int v1 = __builtin_amdgcn_ds_bpermute(aL0, (int)pk1[nfb]);
      int x0 = __builtin_amdgcn_ds_bpermute(aL1, (int)pk0[nfa]);
      int x1 = __builtin_amdgcn_ds_bpermute(aL1, (int)pk0[nfb]);
      int y0 = __builtin_amdgcn_ds_bpermute(aL1, (int)pk1[nfa]);
      int y1 = __builtin_amdgcn_ds_bpermute(aL1, (int)pk1[nfb]);
      u32x4 pw;
      pw[0] = (uint32_t)(hi ? u1 : u0);
      pw[1] = (uint32_t)(hi ? v1 : v0);
      pw[2] = (uint32_t)(hi ? x1 : x0);
      pw[3] = (uint32_t)(hi ? y1 : y0);
      bf16x8 pa = __builtin_bit_cast(bf16x8, pw);
      const int cc = kk ? c1 : c0;
#pragma unroll
      for (int nf = 0; nf < 4; ++nf) {
        bf16x8 vb = *(const bf16x8*)(Vc + nf*1024 + cc);
        oacc[nf] = __builtin_amdgcn_mfma_f32_16x16x32_bf16(pa, vb, oacc[nf], 0, 0, 0);
      }
    }
    __builtin_amdgcn_s_setprio(0);
  }

  const int qb = l4 << 2;
  float li0 = 1.0f / __shfl(lrow, qb + 0);
  float li1 = 1.0f / __shfl(lrow, qb + 1);
  float li2 = 1.0f / __shfl(lrow, qb + 2);
  float li3 = 1.0f / __shfl(lrow, qb + 3);
  bf16* outp = ctx + ((size_t)b * TT + qt * 128 + w * 16) * DD + h * 64;
#pragma unroll
  for (int nf = 0; nf < 4; ++nf) {
    outp[(size_t)(qb + 0) * DD + l15 + nf*16] = (bf16)(oacc[nf][0] * li0);
    outp[(size_t)(qb + 1) * DD + l15 + nf*16] = (bf16)(oacc[nf][1] * li1);
    outp[(size_t)(qb + 2) * DD + l15 + nf*16] = (bf16)(oacc[nf][2] * li2);
    outp[(size_t)(qb + 3) * DD + l15 + nf*16] = (bf16)(oacc[nf][3] * li3);
  }
}

// ---------------------------------------------------------------------------
// launch
// ---------------------------------------------------------------------------
extern "C" void kernel_launch(void* const* d_in, const int* in_sizes, int n_in,
                              void* d_out, int out_size, void* d_ws, size_t ws_size,
                              hipStream_t stream) {
  const float* x     = (const float*)d_in[0];
  const float* ln1_g = (const float*)d_in[1];
  const float* ln1_b = (const float*)d_in[2];
  const float* ln2_g = (const float*)d_in[3];
  const float* ln2_b = (const float*)d_in[4];
  const float* Wq    = (const float*)d_in[5];
  const float* bq    = (const float*)d_in[6];
  const float* Wk    = (const float*)d_in[7];
  const float* bk    = (const float*)d_in[8];
  const float* Wv    = (const float*)d_in[9];
  const float* bv    = (const float*)d_in[10];
  const float* Wo    = (const float*)d_in[11];
  const float* bo    = (const float*)d_in[12];
  const float* W1    = (const float*)d_in[13];
  const float* b1    = (const float*)d_in[14];
  const float* W2    = (const float*)d_in[15];
  const float* b2    = (const float*)d_in[16];
  float* out = (float*)d_out;

  char* ws = (char*)d_ws;
  bf16* h1    = (bf16*)(ws + 0);                    // 16MB (dead after QKV GEMM)
  bf16* vT    = (bf16*)(ws + 0);                    // aliases h1
  bf16* qkv   = (bf16*)(ws + 16777216);             // 48MB
  bf16* ctx   = (bf16*)(ws + 67108864);             // 16MB
  bf16* u     = (bf16*)(ws + 16777216);             // 64MB, aliases qkv+ctx (dead)
  float* x1   = (float*)(ws + 83886080);            // 32MB
  bf16* wtqkv = (bf16*)(ws + 117440512);            // 6MB
  bf16* wot   = (bf16*)(ws + 123731968);            // 2MB
  bf16* w1t   = (bf16*)(ws + 125829120);            // 8MB
  bf16* w2t   = (bf16*)(ws + 134217728);            // 8MB
  float* bqkv = (float*)(ws + 142606336);           // 12KB
  bf16* h2 = h1;

  dim3 tb(32, 8);
  k_transpose_cast<<<dim3(2, 32, 16), tb, 0, stream>>>(Wq, wtqkv, DD, HDIM);
  k_transpose_cast<<<dim3(2, 32, 16), tb, 0, stream>>>(Wk, wtqkv + 1024*1024, DD, HDIM);
  k_transpose_cast<<<dim3(2, 32, 16), tb, 0, stream>>>(Wv, wtqkv + 2048*1024, DD, HDIM);
  k_transpose_cast<<<dim3(32, 32, 1), tb, 0, stream>>>(Wo, wot, DD, DD);
  k_transpose_cast<<<dim3(128, 32, 1), tb, 0, stream>>>(W1, w1t, DD, FFD);
  k_transpose_cast<<<dim3(32, 128, 1), tb, 0, stream>>>(W2, w2t, FFD, DD);
  k_concat_bias<<<dim3(12), 256, 0, stream>>>(bq, bk, bv, bqkv);

  k_layernorm<<<dim3(MROWS), 256, 0, stream>>>(x, ln1_g, ln1_b, h1);

  // QKV: (8192,1024) x (3072,1024)^T -> qkv bf16
  // [gemm256n 256x128: grid 768 = 3/CU exact, fixes 384-block quantization]
  k_gemm256n<0><<<dim3((MROWS/256)*(3072/128)), 512, 0, stream>>>(
      h1, wtqkv, bqkv, qkv, MROWS, 3072, DD);

  k_transpose_v<<<dim3(32, 2, 128), tb, 0, stream>>>(qkv, vT);

  k_attn<<<dim3(1024), 512, 0, stream>>>(qkv, vT, ctx);

  // Wo + residual: x1 = x + ctx@Wo + bo  (f32)
  k_gemm<2><<<dim3(8, 64), 256, 0, stream>>>(ctx, wot, bo, x,
                                             nullptr, x1, MROWS, DD, DD);

  k_layernorm<<<dim3(MROWS), 256, 0, stream>>>(x1, ln2_g, ln2_b, h2);

  // FF1 + GELU -> u bf16   [gemm256p — R12 best]
  k_gemm256p<1><<<dim3((MROWS/256)*(FFD/256)), 512, 0, stream>>>(
      h2, w1t, b1, u, MROWS, FFD, DD);

  // FF2 + residual -> out f32
  k_gemm<2><<<dim3(8, 64), 256, 0, stream>>>(u, w2t, b2, x1,
                                             nullptr, out, MROWS, DD, FFD);

  (void)in_sizes; (void)n_in; (void)out_size; (void)ws_size;
}

// Round 14
// 410.616 us; speedup vs baseline: 1.0098x; 1.0098x over previous
//
#include <hip/hip_runtime.h>
#include <hip/hip_bf16.h>
#include <cstdint>
#include <cstddef>

// ---------------------------------------------------------------------------
// Transformer block: LN1 -> MHA(16 heads, no mask) -> +res -> LN2 -> GELU MLP -> +res
// B=8 T=1024 D=1024 H=16 HD=64 FF=4096.  bf16 MFMA everywhere, fp32 accum.
// ---------------------------------------------------------------------------

typedef __bf16 bf16;
typedef __bf16 bf16x8 __attribute__((ext_vector_type(8)));
typedef __bf16 bf16x4 __attribute__((ext_vector_type(4)));
typedef float  f32x4  __attribute__((ext_vector_type(4)));
typedef uint32_t u32x4 __attribute__((ext_vector_type(4)));

#define BB    8
#define TT    1024
#define DD    1024
#define HH    16
#define HDIM  64
#define FFD   4096
#define MROWS (BB*TT)   // 8192

// async global->LDS, 16B per lane, LDS dest = wave-uniform base + lane*16
__device__ __forceinline__ void async_ld16(const void* g, void* l) {
  __builtin_amdgcn_global_load_lds(
      (const __attribute__((address_space(1))) uint32_t*)g,
      (__attribute__((address_space(3))) uint32_t*)l, 16, 0, 0);
}

// cheap GELU (tanh form, |err vs erf-form| <~1e-3, absorbed by bf16 out)
__device__ __forceinline__ float gelu_f(float v) {
  float z = 0.7978845608028654f * (v + 0.044715f * v * v * v);
  z = fminf(fmaxf(z, -9.0f), 9.0f);
  const float e = __expf(-2.0f * z);
  const float th = 1.0f - __fdividef(2.0f * e, 1.0f + e);
  return 0.5f * v * (1.0f + th);
}

// raw v_exp_f32: 2^x
__device__ __forceinline__ float exp2_fast(float x) {
  float r; asm("v_exp_f32 %0, %1" : "=v"(r) : "v"(x)); return r;
}
// packed f32->bf16 pair (no builtin on gfx950)
__device__ __forceinline__ uint32_t cvt_pk_bf16(float a, float b) {
  uint32_t r; asm("v_cvt_pk_bf16_f32 %0, %1, %2" : "=v"(r) : "v"(a), "v"(b));
  return r;
}

// ---------------------------------------------------------------------------
// Weight repack: src (K,N) f32 row-major -> dst (N,K) bf16 row-major (B^T)
// ---------------------------------------------------------------------------
__global__ void k_transpose_cast(const float* __restrict__ src, bf16* __restrict__ dst,
                                 int K, int N) {
  __shared__ float tile[32][33];
  const size_t boff = (size_t)blockIdx.z * K * N;
  src += boff; dst += boff;
  const int k0 = blockIdx.y * 32, n0 = blockIdx.x * 32;
  const int tx = threadIdx.x, ty = threadIdx.y; // (32,8)
#pragma unroll
  for (int i = 0; i < 4; ++i)
    tile[ty + i*8][tx] = src[(size_t)(k0 + ty + i*8) * N + n0 + tx];
  __syncthreads();
#pragma unroll
  for (int i = 0; i < 4; ++i)
    dst[(size_t)(n0 + ty + i*8) * K + k0 + tx] = (bf16)tile[tx][ty + i*8];
}

// merged Q/K/V per-head repack: z in [0,48): matrix = z/16, head = z%16.
// each (D, HD) head block -> rows of wtqkv (3072, 1024).
__global__ void k_transpose_qkv(const float* __restrict__ Wq, const float* __restrict__ Wk,
                                const float* __restrict__ Wv, bf16* __restrict__ dst) {
  __shared__ float tile[32][33];
  const int z = blockIdx.z;
  const int mm = z >> 4, hh = z & 15;
  const float* src = (mm == 0 ? Wq : mm == 1 ? Wk : Wv) + (size_t)hh * DD * HDIM;
  bf16* d = dst + ((size_t)mm * DD + (size_t)hh * HDIM) * DD;  // row (mm*1024+hh*64)
  const int k0 = blockIdx.y * 32, n0 = blockIdx.x * 32;        // k in [0,1024), n in [0,64)
  const int tx = threadIdx.x, ty = threadIdx.y; // (32,8)
#pragma unroll
  for (int i = 0; i < 4; ++i)
    tile[ty + i*8][tx] = src[(size_t)(k0 + ty + i*8) * HDIM + n0 + tx];
  __syncthreads();
#pragma unroll
  for (int i = 0; i < 4; ++i)
    d[(size_t)(n0 + ty + i*8) * DD + k0 + tx] = (bf16)tile[tx][ty + i*8];
}

__global__ void k_concat_bias(const float* __restrict__ bq, const float* __restrict__ bk,
                              const float* __restrict__ bv, float* __restrict__ out) {
  int i = blockIdx.x * 256 + threadIdx.x; // 3072
  float v = (i < 1024) ? bq[i] : (i < 2048) ? bk[i - 1024] : bv[i - 2048];
  out[i] = v;
}

// V part of qkv (B*T, 3072) -> vT[b][h][e][t]
__global__ void k_transpose_v(const bf16* __restrict__ qkv, bf16* __restrict__ vT) {
  __shared__ bf16 tile[32][33];
  const int bh = blockIdx.z;
  const int b = bh >> 4, h = bh & 15;
  const int t0 = blockIdx.x * 32, e0 = blockIdx.y * 32;
  const int tx = threadIdx.x, ty = threadIdx.y; // (32,8)
  const bf16* src = qkv + (size_t)b * TT * 3072 + 2048 + h * 64;
#pragma unroll
  for (int i = 0; i < 4; ++i)
    tile[ty + i*8][tx] = src[(size_t)(t0 + ty + i*8) * 3072 + e0 + tx];
  __syncthreads();
  bf16* dst = vT + ((size_t)bh * 64 + e0) * TT + t0;
#pragma unroll
  for (int i = 0; i < 4; ++i)
    dst[(size_t)(ty + i*8) * TT + tx] = tile[tx][ty + i*8];
}

// ---------------------------------------------------------------------------
// LayerNorm: one block per row (D=1024), 256 threads, f32 in -> bf16 out
// ---------------------------------------------------------------------------
__global__ void k_layernorm(const float* __restrict__ x, const float* __restrict__ g,
                            const float* __restrict__ b, bf16* __restrict__ out) {
  const int row = blockIdx.x, tid = threadIdx.x;
  const float* xr = x + (size_t)row * DD;
  f32x4 v = *(const f32x4*)(xr + tid * 4);
  float s  = v[0] + v[1] + v[2] + v[3];
  float ss = v[0]*v[0] + v[1]*v[1] + v[2]*v[2] + v[3]*v[3];
#pragma unroll
  for (int m = 1; m < 64; m <<= 1) { s += __shfl_xor(s, m); ss += __shfl_xor(ss, m); }
  __shared__ float red[8];
  const int wid = tid >> 6;
  if ((tid & 63) == 0) { red[wid*2] = s; red[wid*2+1] = ss; }
  __syncthreads();
  s  = red[0] + red[2] + red[4] + red[6];
  ss = red[1] + red[3] + red[5] + red[7];
  const float mu = s * (1.0f / DD);
  const float var = ss * (1.0f / DD) - mu * mu;
  const float rs = rsqrtf(var + 1e-5f);
  bf16x4 o;
#pragma unroll
  for (int j = 0; j < 4; ++j)
    o[j] = (bf16)((v[j] - mu) * rs * g[tid*4 + j] + b[tid*4 + j]);
  *(bf16x4*)&out[(size_t)row * DD + tid * 4] = o;
}

// ---------------------------------------------------------------------------
// Shared helper macros for 256-tile 8-wave GEMMs
// ---------------------------------------------------------------------------
#define RD_B(reg, base) { _Pragma("unroll") \
    for (int nf = 0; nf < 4; ++nf) reg[nf] = *(const bf16x8*)((base) + nf*1024); }
#define RD_A4(reg, base, mb) { _Pragma("unroll") \
    for (int mf = 0; mf < 4; ++mf) reg[mf] = *(const bf16x8*)((base) + (mb+mf)*1024); }
#define MM(areg, breg, mb) { _Pragma("unroll") \
    for (int mf = 0; mf < 4; ++mf) _Pragma("unroll") \
      for (int nf = 0; nf < 4; ++nf) \
        acc[mb+mf][nf] = __builtin_amdgcn_mfma_f32_16x16x32_bf16(areg[mf], breg[nf], acc[mb+mf][nf], 0, 0, 0); }
#define SGA(off, lb) { async_ld16(aG0 + (off), (lb)+0*64);   async_ld16(aG1 + (off), (lb)+64*64); \
                       async_ld16(aG2 + (off), (lb)+128*64); async_ld16(aG3 + (off), (lb)+192*64); }
// half-tile stages (2 loads each)
#define SGA_S0(off, lb) { async_ld16(aG0 + (off), (lb)+0*64);    async_ld16(aG2 + (off), (lb)+128*64); }
#define SGA_S1(off, lb) { async_ld16(aG1 + (off), (lb)+64*64);   async_ld16(aG3 + (off), (lb)+192*64); }
#define SGB_Q0(off, lb) { async_ld16(bG0 + (off), (lb)+0*64);    async_ld16(bG1 + (off), (lb)+64*64); }
#define SGB_Q1(off, lb) { async_ld16(bG2 + (off), (lb)+128*64);  async_ld16(bG3 + (off), (lb)+192*64); }
#define WAIT_LGKM { asm volatile("s_waitcnt lgkmcnt(0)" ::: "memory"); __builtin_amdgcn_sched_barrier(0); }
#define VMC(n)  { asm volatile("s_waitcnt vmcnt(" #n ")" ::: "memory"); __builtin_amdgcn_sched_barrier(0); }
#define BAR __builtin_amdgcn_s_barrier()
#define PR1 __builtin_amdgcn_s_setprio(1)
#define PR0 __builtin_amdgcn_s_setprio(0)

// ---------------------------------------------------------------------------
// k_gemm256n: 256x128 tile, 8 waves (4x2), BK=64, LDS 96 KB. QKV kernel
// (grid 768 = 3/CU exact; fixes 384-block quantization of 256x256).
// 2 phases/tile {8 ds_read; bar; lgkm0; 16 MFMA; bar}; full tile t+2 (6 loads)
// staged after last-reader barrier; boundary vmcnt(6).
// MODE 0: bf16 bias | MODE 1: bf16 gelu(bias)
// ---------------------------------------------------------------------------
template<int MODE>
__global__ __launch_bounds__(512, 2)
void k_gemm256n(const bf16* __restrict__ A, const bf16* __restrict__ Bt,
                const float* __restrict__ bias, bf16* __restrict__ outb,
                int M, int N, int K) {
  __shared__ __align__(16) bf16 As[2][256 * 64];   // 64 KB
  __shared__ __align__(16) bf16 Bs[2][128 * 64];   // 32 KB
  const int tid = threadIdx.x;
  const int w = tid >> 6, l = tid & 63;
  const int wm = w >> 1, wn = w & 1;               // 4 x 2 waves
  const int l15 = l & 15, l4 = l >> 4;
  const int nbx = N >> 7;                          // 128-wide column tiles
  const int nwg = gridDim.x;
  const int cpx = nwg >> 3;
  const int swz = (blockIdx.x & 7) * cpx + (blockIdx.x >> 3);
  const int m0 = (swz / nbx) << 8, n0 = (swz % nbx) << 7;
  f32x4 acc[4][4] = {};
  const int l7 = l15 & 7;
  const int c0 = (l4 ^ l7) * 8;
  const int c1 = ((4 + l4) ^ l7) * 8;
  const bf16* const A00 = &As[0][(wm*64 + l15)*64 + c0];
  const bf16* const A01 = &As[0][(wm*64 + l15)*64 + c1];
  const bf16* const A10 = &As[1][(wm*64 + l15)*64 + c0];
  const bf16* const A11 = &As[1][(wm*64 + l15)*64 + c1];
  const bf16* const B00 = &Bs[0][(wn*64 + l15)*64 + c0];
  const bf16* const B01 = &Bs[0][(wn*64 + l15)*64 + c1];
  const bf16* const B10 = &Bs[1][(wn*64 + l15)*64 + c0];
  const bf16* const B11 = &Bs[1][(wn*64 + l15)*64 + c1];
  const int srow = l >> 3, sch = l & 7;
  const int schx = (sch ^ srow) * 8;
  const bf16* const aG0 = A  + (size_t)(m0 + w*8 + srow) * K + schx;
  const bf16* const aG1 = aG0 + (size_t)64 * K;
  const bf16* const aG2 = aG0 + (size_t)128 * K;
  const bf16* const aG3 = aG0 + (size_t)192 * K;
  const bf16* const bG0 = Bt + (size_t)(n0 + w*8 + srow) * K + schx;
  const bf16* const bG1 = bG0 + (size_t)64 * K;
  bf16* const LA0 = (bf16*)As[0] + w*512;
  bf16* const LA1 = (bf16*)As[1] + w*512;
  bf16* const LB0 = (bf16*)Bs[0] + w*512;
  bf16* const LB1 = (bf16*)Bs[1] + w*512;
  const int NT = K >> 6;   // even

#define SGB2(off, lb) { async_ld16(bG0 + (off), (lb)+0*64); async_ld16(bG1 + (off), (lb)+64*64); }

  // prologue: tile0 -> buf0 (6), tile1 -> buf1 (6); drain tile0
  SGA(0, LA0)  SGB2(0, LB0)
  SGA(64, LA1) SGB2(64, LB1)
  VMC(6);
  BAR;

  size_t ko = 0;
  for (int T = 0; T < NT; T += 2) {
    const bool nl  = (T + 2 < NT);
    const bool nl2 = (T + 3 < NT);
    bf16x8 b0[4], b1[4], a[4], a2[4];

    // ===== tile T (buf0) =====
    RD_B(b0, B00) RD_A4(a, A00, 0)
    BAR; WAIT_LGKM;
    PR1; MM(a, b0, 0) PR0;
    BAR;
    RD_B(b1, B01) RD_A4(a2, A01, 0)
    BAR; WAIT_LGKM;
    PR1; MM(a2, b1, 0) PR0;
    BAR;                                   // all buf0 reads drained on ALL waves
    if (nl) { SGA(ko + 128, LA0) SGB2(ko + 128, LB0) }   // tile T+2 -> buf0
    if (nl) { VMC(6); } else { VMC(0); }   // t+1 landed; t+2 in flight
    BAR;

    // ===== tile T+1 (buf1) =====
    RD_B(b0, B10) RD_A4(a, A10, 0)
    BAR; WAIT_LGKM;
    PR1; MM(a, b0, 0) PR0;
    BAR;
    RD_B(b1, B11) RD_A4(a2, A11, 0)
    BAR; WAIT_LGKM;
    PR1; MM(a2, b1, 0) PR0;
    BAR;                                   // all buf1 reads drained
    if (nl2) { SGA(ko + 192, LA1) SGB2(ko + 192, LB1) }  // tile T+3 -> buf1
    if (nl2) { VMC(6); } else { VMC(0); }
    BAR;

    ko += 128;
  }
#undef SGB2

  // epilogue
#pragma unroll
  for (int mf = 0; mf < 4; ++mf) {
#pragma unroll
    for (int r = 0; r < 4; ++r) {
      const size_t grow = (size_t)(m0 + wm*64 + mf*16 + l4*4 + r);
      const size_t rowoff = grow * (size_t)N;
#pragma unroll
      for (int nf = 0; nf < 4; ++nf) {
        const int gcol = n0 + wn*64 + nf*16 + l15;
        float v = acc[mf][nf][r] + bias[gcol];
        if constexpr (MODE == 1) v = gelu_f(v);
        outb[rowoff + gcol] = (bf16)v;
      }
    }
  }
}

// ---------------------------------------------------------------------------
// k_gemm256p: 256x256 per-phase interleave (677 TF at FF1 shape). FF1 kernel.
// ---------------------------------------------------------------------------
template<int MODE>
__global__ __launch_bounds__(512, 2)
void k_gemm256p(const bf16* __restrict__ A, const bf16* __restrict__ Bt,
                const float* __restrict__ bias, bf16* __restrict__ outb,
                int M, int N, int K) {
  __shared__ __align__(16) bf16 As[2][256 * 64];
  __shared__ __align__(16) bf16 Bs[2][256 * 64];
  const int tid = threadIdx.x;
  const int w = tid >> 6, l = tid & 63;
  const int wm = w >> 2, wn = w & 3;
  const int l15 = l & 15, l4 = l >> 4;
  const int nbx = N >> 8;
  const int nwg = gridDim.x;
  const int cpx = nwg >> 3;
  const int swz = (blockIdx.x & 7) * cpx + (blockIdx.x >> 3);
  const int m0 = (swz / nbx) << 8, n0 = (swz % nbx) << 8;
  f32x4 acc[8][4] = {};
  const int l7 = l15 & 7;
  const int c0 = (l4 ^ l7) * 8;
  const int c1 = ((4 + l4) ^ l7) * 8;
  const bf16* const A00 = &As[0][(wm*128 + l15)*64 + c0];
  const bf16* const A01 = &As[0][(wm*128 + l15)*64 + c1];
  const bf16* const A10 = &As[1][(wm*128 + l15)*64 + c0];
  const bf16* const A11 = &As[1][(wm*128 + l15)*64 + c1];
  const bf16* const B00 = &Bs[0][(wn*64 + l15)*64 + c0];
  const bf16* const B01 = &Bs[0][(wn*64 + l15)*64 + c1];
  const bf16* const B10 = &Bs[1][(wn*64 + l15)*64 + c0];
  const bf16* const B11 = &Bs[1][(wn*64 + l15)*64 + c1];
  const int srow = l >> 3, sch = l & 7;
  const int schx = (sch ^ srow) * 8;
  const bf16* const aG0 = A  + (size_t)(m0 + w*8 + srow) * K + schx;
  const bf16* const aG1 = aG0 + (size_t)64 * K;
  const bf16* const aG2 = aG0 + (size_t)128 * K;
  const bf16* const aG3 = aG0 + (size_t)192 * K;
  const bf16* const bG0 = Bt + (size_t)(n0 + w*8 + srow) * K + schx;
  const bf16* const bG1 = bG0 + (size_t)64 * K;
  const bf16* const bG2 = bG0 + (size_t)128 * K;
  const bf16* const bG3 = bG0 + (size_t)192 * K;
  bf16* const LA0 = (bf16*)As[0] + w*512;
  bf16* const LA1 = (bf16*)As[1] + w*512;
  bf16* const LB0 = (bf16*)Bs[0] + w*512;
  bf16* const LB1 = (bf16*)Bs[1] + w*512;
  const int NT = K >> 6;

  // prologue: A(0)+B(0) -> buf0 (8 loads), Ah0(1) -> buf1 (2 loads)
  SGA_S0(0, LA0) SGA_S1(0, LA0)
  SGB_Q0(0, LB0) SGB_Q1(0, LB0)
  SGA_S0(64, LA1)
  VMC(2);
  BAR;

  size_t ko = 0;
  for (int T = 0; T < NT; T += 2) {
    const bool s2 = (T + 2 < NT);
    const bool s3 = (T + 3 < NT);
    bf16x8 b0[4], b1[4], a[4];

    // ===== tile T (buf0) =====
    RD_B(b0, B00) RD_A4(a, A00, 0)
    SGA_S1(ko + 64, LA1)
    BAR; WAIT_LGKM;
    PR1; MM(a, b0, 0) PR0;
    BAR;
    RD_B(b1, B01) RD_A4(a, A01, 0)
    SGB_Q0(ko + 64, LB1)
    BAR; WAIT_LGKM;
    PR1; MM(a, b1, 0) PR0;
    BAR;
    RD_A4(a, A00, 4)
    SGB_Q1(ko + 64, LB1)
    BAR; WAIT_LGKM;
    PR1; MM(a, b0, 4) PR0;
    BAR;
    RD_A4(a, A01, 4)
    if (s2) SGA_S0(ko + 128, LA0)
    BAR; WAIT_LGKM;
    PR1; MM(a, b1, 4) PR0;
    if (s2) { VMC(2); } else { VMC(0); }
    BAR;

    // ===== tile T+1 (buf1) =====
    RD_B(b0, B10) RD_A4(a, A10, 0)
    if (s2) SGA_S1(ko + 128, LA0)
    BAR; WAIT_LGKM;
    PR1; MM(a, b0, 0) PR0;
    BAR;
    RD_B(b1, B11) RD_A4(a, A11, 0)
    if (s2) SGB_Q0(ko + 128, LB0)
    BAR; WAIT_LGKM;
    PR1; MM(a, b1, 0) PR0;
    BAR;
    RD_A4(a, A10, 4)
    if (s2) SGB_Q1(ko + 128, LB0)
    BAR; WAIT_LGKM;
    PR1; MM(a, b0, 4) PR0;
    BAR;
    RD_A4(a, A11, 4)
    if (s3) SGA_S0(ko + 192, LA1)
    BAR; WAIT_LGKM;
    PR1; MM(a, b1, 4) PR0;
    if (s3) { VMC(2); } else { VMC(0); }
    BAR;

    ko += 128;
  }

  // epilogue
#pragma unroll
  for (int mf = 0; mf < 8; ++mf) {
#pragma unroll
    for (int r = 0; r < 4; ++r) {
      const size_t grow = (size_t)(m0 + wm*128 + mf*16 + l4*4 + r);
      const size_t rowoff = grow * (size_t)N;
#pragma unroll
      for (int nf = 0; nf < 4; ++nf) {
        const int gcol = n0 + wn*64 + nf*16 + l15;
        float v = acc[mf][nf][r] + bias[gcol];
        if constexpr (MODE == 1) v = gelu_f(v);
        outb[rowoff + gcol] = (bf16)v;
      }
    }
  }
}

// ---------------------------------------------------------------------------
// GEMM 128x128 (Wo: N=1024 K=1024, FF2: N=1024 K=4096). MODE 2: f32 bias+res.
// ---------------------------------------------------------------------------
template<int MODE>
__global__ __launch_bounds__(256)
void k_gemm(const bf16* __restrict__ A, const bf16* __restrict__ Bt,
            const float* __restrict__ bias, const float* __restrict__ res,
            bf16* __restrict__ outb, float* __restrict__ outf,
            int M, int N, int K) {
  __shared__ __align__(16) bf16 As[128 * 64];
  __shared__ __align__(16) bf16 Bs[128 * 64];
  const int tid = threadIdx.x;
  const int w = tid >> 6, l = tid & 63;
  const int wm = w >> 1, wn = w & 1;
  const int l15 = l & 15, l4 = l >> 4;
  const int m0 = blockIdx.y * 128, n0 = blockIdx.x * 128;

  f32x4 acc[4][4] = {};

  const int l7 = l15 & 7;
  const int c0 = (l4 ^ l7) * 8, c1 = ((4 + l4) ^ l7) * 8;
  const bf16* const Ab = &As[(wm*64 + l15)*64];
  const bf16* const Bb = &Bs[(wn*64 + l15)*64];

  const int sr8 = l >> 3, sl7 = l & 7;
  const int schx = (sl7 ^ sr8) * 8;
  const bf16* const gA0 = A  + (size_t)(m0 + w*32 + sr8) * K + schx;
  const bf16* const gA1 = gA0 + (size_t)8 * K;
  const bf16* const gA2 = gA0 + (size_t)16 * K;
  const bf16* const gA3 = gA0 + (size_t)24 * K;
  const bf16* const gB0 = Bt + (size_t)(n0 + w*32 + sr8) * K + schx;
  const bf16* const gB1 = gB0 + (size_t)8 * K;
  const bf16* const gB2 = gB0 + (size_t)16 * K;
  const bf16* const gB3 = gB0 + (size_t)24 * K;
  bf16* const lA = (bf16*)As + w*32*64;
  bf16* const lB = (bf16*)Bs + w*32*64;

  for (int k0 = 0; k0 < K; k0 += 64) {
    async_ld16(gA0 + k0, lA);          async_ld16(gA1 + k0, lA + 8*64);
    async_ld16(gA2 + k0, lA + 16*64);  async_ld16(gA3 + k0, lA + 24*64);
    async_ld16(gB0 + k0, lB);          async_ld16(gB1 + k0, lB + 8*64);
    async_ld16(gB2 + k0, lB + 16*64);  async_ld16(gB3 + k0, lB + 24*64);
    __syncthreads();
#pragma unroll
    for (int kk = 0; kk < 2; ++kk) {
      const int cc = kk ? c1 : c0;
      bf16x8 af[4], bfr[4];
#pragma unroll
      for (int mf = 0; mf < 4; ++mf) af[mf] = *(const bf16x8*)(Ab + mf*1024 + cc);
#pragma unroll
      for (int nf = 0; nf < 4; ++nf) bfr[nf] = *(const bf16x8*)(Bb + nf*1024 + cc);
#pragma unroll
      for (int mf = 0; mf < 4; ++mf)
#pragma unroll
        for (int nf = 0; nf < 4; ++nf)
          acc[mf][nf] = __builtin_amdgcn_mfma_f32_16x16x32_bf16(af[mf], bfr[nf], acc[mf][nf], 0, 0, 0);
    }
    __syncthreads();
  }

#pragma unroll
  for (int mf = 0; mf < 4; ++mf) {
#pragma unroll
    for (int r = 0; r < 4; ++r) {
      const size_t grow = (size_t)(m0 + wm*64 + mf*16 + l4*4 + r);
      const size_t rowoff = grow * (size_t)N;
#pragma unroll
      for (int nf = 0; nf < 4; ++nf) {
        const int gcol = n0 + wn*64 + nf*16 + l15;
        float v = acc[mf][nf][r] + bias[gcol];
        if constexpr (MODE == 1) v = gelu_f(v);
        if constexpr (MODE == 2) {
          v += res[rowoff + gcol];
          outf[rowoff + gcol] = v;
        } else {
          outb[rowoff + gcol] = (bf16)v;
        }
      }
    }
  }
}

// ---------------------------------------------------------------------------
// Flash attention v4 (R7, unchanged): swapped QK^T (lane owns q=l15),
// in-register P via cvt_pk + ds_bpermute; 512 thr = 8 waves x 16 q-rows;
// KV tiles 64, dbuf swizzled LDS (32 KB); XCD-chunked grid; defer-max.
// ---------------------------------------------------------------------------
__global__ __launch_bounds__(512)
void k_attn(const bf16* __restrict__ qkv, const bf16* __restrict__ vT,
            bf16* __restrict__ ctx) {
  const int tid = threadIdx.x;
  const int w = tid >> 6, l = tid & 63;
  const int l15 = l & 15, l4 = l >> 4;

  const int gid = ((int)blockIdx.x & 7) * 128 + ((int)blockIdx.x >> 3);
  const int qt = gid & 7;
  const int bh = gid >> 3;
  const int h = bh & 15, b = bh >> 4;

  __shared__ __align__(16) bf16 Ks[2][64 * 64];
  __shared__ __align__(16) bf16 Vs[2][64 * 64];

  const bf16* base = qkv + (size_t)b * TT * 3072;
  const bf16* Qp = base + h * 64;
  const bf16* Kp = base + 1024 + h * 64;
  const bf16* Vtp = vT + (size_t)bh * HDIM * TT;

  const float SCL = 0.125f * 1.44269504f;
  const float THR = 8.0f * 1.44269504f;

  const int qrow = qt * 128 + w * 16 + l15;
  bf16x8 qf[2];
  {
    bf16x8 q0 = *(const bf16x8*)&Qp[(size_t)qrow * 3072 + l4 * 8];
    bf16x8 q1 = *(const bf16x8*)&Qp[(size_t)qrow * 3072 + 32 + l4 * 8];
#pragma unroll
    for (int j = 0; j < 8; ++j) {
      qf[0][j] = (bf16)((float)q0[j] * SCL);
      qf[1][j] = (bf16)((float)q1[j] * SCL);
    }
  }

  f32x4 oacc[4] = {};
  float mrow = -1e30f;
  float lrow = 0.f;

  const int l7 = l15 & 7;
  const int c0 = (l4 ^ l7) * 8, c1 = ((4 + l4) ^ l7) * 8;

  const int aL0 = (((l4 & 1) << 5) + l15) << 2;
  const int aL1 = aL0 + 64;
  const bool hi = (l & 32) != 0;

  const int srow = w * 8 + (l >> 3);
  const int sch = (l & 7) ^ (srow & 7);

  auto stage = [&](int buf, int t) {
    const int kv0 = t * 64;
    async_ld16(Kp + (size_t)(kv0 + srow) * 3072 + sch * 8, &Ks[buf][w * 512]);
    async_ld16(Vtp + (size_t)srow * TT + kv0 + sch * 8, &Vs[buf][w * 512]);
  };

  stage(0, 0);
  for (int t = 0; t < TT / 64; ++t) {
    const int cur = t & 1;
    __syncthreads();
    if (t + 1 < TT / 64) stage(cur ^ 1, t + 1);

    const bf16* const Kc = &Ks[cur][l15 * 64];
    const bf16* const Vc = &Vs[cur][l15 * 64];

    f32x4 sacc[4] = {};
    __builtin_amdgcn_s_setprio(1);
#pragma unroll
    for (int nf = 0; nf < 4; ++nf) {
      bf16x8 k0 = *(const bf16x8*)(Kc + nf*1024 + c0);
      bf16x8 k1 = *(const bf16x8*)(Kc + nf*1024 + c1);
      sacc[nf] = __builtin_amdgcn_mfma_f32_16x16x32_bf16(k0, qf[0], sacc[nf], 0, 0, 0);
      sacc[nf] = __builtin_amdgcn_mfma_f32_16x16x32_bf16(k1, qf[1], sacc[nf], 0, 0, 0);
    }
    __builtin_amdgcn_s_setprio(0);

    float m = fmaxf(fmaxf(sacc[0][0], sacc[0][1]), fmaxf(sacc[0][2], sacc[0][3]));
#pragma unroll
    for (int nf = 1; nf < 4; ++nf)
      m = fmaxf(m, fmaxf(fmaxf(sacc[nf][0], sacc[nf][1]), fmaxf(sacc[nf][2], sacc[nf][3])));
    m = fmaxf(m, __shfl_xor(m, 16));
    m = fmaxf(m, __shfl_xor(m, 32));

    const int ok = (m <= mrow + THR);
    if (!__all(ok)) {
      const float mn = fmaxf(mrow, m);
      const float e = exp2_fast(mrow - mn);
      mrow = mn;
      lrow *= e;
      const int qb = l4 << 2;
      float e0 = __shfl(e, qb + 0), e1 = __shfl(e, qb + 1);
      float e2 = __shfl(e, qb + 2), e3 = __shfl(e, qb + 3);
#pragma unroll
      for (int nf = 0; nf < 4; ++nf) {
        oacc[nf][0] *= e0; oacc[nf][1] *= e1;
        oacc[nf][2] *= e2; oacc[nf][3] *= e3;
      }
    }

    float p[4][4];
    float ls = 0.f;
    uint32_t pk0[4], pk1[4];
#pragma unroll
    for (int nf = 0; nf < 4; ++nf) {
#pragma unroll
      for (int r = 0; r < 4; ++r) {
        p[nf][r] = exp2_fast(sacc[nf][r] - mrow);
        ls += p[nf][r];
      }
      pk0[nf] = cvt_pk_bf16(p[nf][0], p[nf][1]);
      pk1[nf] = cvt_pk_bf16(p[nf][2], p[nf][3]);
    }
    ls += __shfl_xor(ls, 16);
    ls += __shfl_xor(ls, 32);
    lrow += ls;

    __builtin_amdgcn_s_setprio(1);
#pragma unroll
    for (int kk = 0; kk < 2; ++kk) {
      const int nfa = 2*kk, nfb = 2*kk + 1;
      int u0 = __builtin_amdgcn_ds_bpermute(aL0, (int)pk0[nfa]);
      int u1 = __builtin_amdgcn_ds_bpermute(aL0, (int)pk0[nfb]);
      int v0 = __builtin_amdgcn_ds_bpermute(aL0, (int)pk1[nfa]);
      int v1 = __builtin_amdgcn_ds_bpermute(aL0, (int)pk1[nfb]);
      int x0 = __builtin_amdgcn_ds_bpermute(aL1, (int)pk0[nfa]);
      int x1 = __builtin_amdgcn_ds_bpermute(aL1, (int)pk0[nfb]);
      int y0 = __builtin_amdgcn_ds_bpermute(aL1, (int)pk1[nfa]);
      int y1 = __builtin_amdgcn_ds_bpermute(aL1, (int)pk1[nfb]);
      u32x4 pw;
      pw[0] = (uint32_t)(hi ? u1 : u0);
      pw[1] = (uint32_t)(hi ? v1 : v0);
      pw[2] = (uint32_t)(hi ? x1 : x0);
      pw[3] = (uint32_t)(hi ? y1 : y0);
      bf16x8 pa = __builtin_bit_cast(bf16x8, pw);
      const int cc = kk ? c1 : c0;
#pragma unroll
      for (int nf = 0; nf < 4; ++nf) {
        bf16x8 vb = *(const bf16x8*)(Vc + nf*1024 + cc);
        oacc[nf] = __builtin_amdgcn_mfma_f32_16x16x32_bf16(pa, vb, oacc[nf], 0, 0, 0);
      }
    }
    __builtin_amdgcn_s_setprio(0);
  }

  const int qb = l4 << 2;
  float li0 = 1.0f / __shfl(lrow, qb + 0);
  float li1 = 1.0f / __shfl(lrow, qb + 1);
  float li2 = 1.0f / __shfl(lrow, qb + 2);
  float li3 = 1.0f / __shfl(lrow, qb + 3);
  bf16* outp = ctx + ((size_t)b * TT + qt * 128 + w * 16) * DD + h * 64;
#pragma unroll
  for (int nf = 0; nf < 4; ++nf) {
    outp[(size_t)(qb + 0) * DD + l15 + nf*16] = (bf16)(oacc[nf][0] * li0);
    outp[(size_t)(qb + 1) * DD + l15 + nf*16] = (bf16)(oacc[nf][1] * li1);
    outp[(size_t)(qb + 2) * DD + l15 + nf*16] = (bf16)(oacc[nf][2] * li2);
    outp[(size_t)(qb + 3) * DD + l15 + nf*16] = (bf16)(oacc[nf][3] * li3);
  }
}

// ---------------------------------------------------------------------------
// launch
// ---------------------------------------------------------------------------
extern "C" void kernel_launch(void* const* d_in, const int* in_sizes, int n_in,
                              void* d_out, int out_size, void* d_ws, size_t ws_size,
                              hipStream_t stream) {
  const float* x     = (const float*)d_in[0];
  const float* ln1_g = (const float*)d_in[1];
  const float* ln1_b = (const float*)d_in[2];
  const float* ln2_g = (const float*)d_in[3];
  const float* ln2_b = (const float*)d_in[4];
  const float* Wq    = (const float*)d_in[5];
  const float* bq    = (const float*)d_in[6];
  const float* Wk    = (const float*)d_in[7];
  const float* bk    = (const float*)d_in[8];
  const float* Wv    = (const float*)d_in[9];
  const float* bv    = (const float*)d_in[10];
  const float* Wo    = (const float*)d_in[11];
  const float* bo    = (const float*)d_in[12];
  const float* W1    = (const float*)d_in[13];
  const float* b1    = (const float*)d_in[14];
  const float* W2    = (const float*)d_in[15];
  const float* b2    = (const float*)d_in[16];
  float* out = (float*)d_out;

  char* ws = (char*)d_ws;
  bf16* h1    = (bf16*)(ws + 0);                    // 16MB (dead after QKV GEMM)
  bf16* vT    = (bf16*)(ws + 0);                    // aliases h1
  bf16* qkv   = (bf16*)(ws + 16777216);             // 48MB
  bf16* ctx   = (bf16*)(ws + 67108864);             // 16MB
  bf16* u     = (bf16*)(ws + 16777216);             // 64MB, aliases qkv+ctx (dead)
  float* x1   = (float*)(ws + 83886080);            // 32MB
  bf16* wtqkv = (bf16*)(ws + 117440512);            // 6MB
  bf16* wot   = (bf16*)(ws + 123731968);            // 2MB
  bf16* w1t   = (bf16*)(ws + 125829120);            // 8MB
  bf16* w2t   = (bf16*)(ws + 134217728);            // 8MB
  float* bqkv = (float*)(ws + 142606336);           // 12KB
  bf16* h2 = h1;

  dim3 tb(32, 8);
  // merged Q/K/V per-head repack (1 launch instead of 3)
  k_transpose_qkv<<<dim3(2, 32, 48), tb, 0, stream>>>(Wq, Wk, Wv, wtqkv);
  k_transpose_cast<<<dim3(32, 32, 1), tb, 0, stream>>>(Wo, wot, DD, DD);
  k_transpose_cast<<<dim3(128, 32, 1), tb, 0, stream>>>(W1, w1t, DD, FFD);
  k_transpose_cast<<<dim3(32, 128, 1), tb, 0, stream>>>(W2, w2t, FFD, DD);
  k_concat_bias<<<dim3(12), 256, 0, stream>>>(bq, bk, bv, bqkv);

  k_layernorm<<<dim3(MROWS), 256, 0, stream>>>(x, ln1_g, ln1_b, h1);

  // QKV: (8192,1024) x (3072,1024)^T -> qkv bf16
  // [gemm256n 256x128: grid 768 = 3/CU exact]
  k_gemm256n<0><<<dim3((MROWS/256)*(3072/128)), 512, 0, stream>>>(
      h1, wtqkv, bqkv, qkv, MROWS, 3072, DD);

  k_transpose_v<<<dim3(32, 2, 128), tb, 0, stream>>>(qkv, vT);

  k_attn<<<dim3(1024), 512, 0, stream>>>(qkv, vT, ctx);

  // Wo + residual: x1 = x + ctx@Wo + bo  (f32)
  k_gemm<2><<<dim3(8, 64), 256, 0, stream>>>(ctx, wot, bo, x,
                                             nullptr, x1, MROWS, DD, DD);

  k_layernorm<<<dim3(MROWS), 256, 0, stream>>>(x1, ln2_g, ln2_b, h2);

  // FF1 + GELU -> u bf16   [gemm256p]
  k_gemm256p<1><<<dim3((MROWS/256)*(FFD/256)), 512, 0, stream>>>(
      h2, w1t, b1, u, MROWS, FFD, DD);

  // FF2 + residual -> out f32
  k_gemm<2><<<dim3(8, 64), 256, 0, stream>>>(u, w2t, b2, x1,
                                             nullptr, out, MROWS, DD, FFD);

  (void)in_sizes; (void)n_in; (void)out_size; (void)ws_size;
}

// Round 15
// 401.590 us; speedup vs baseline: 1.0325x; 1.0225x over previous
//
#include <hip/hip_runtime.h>
#include <hip/hip_bf16.h>
#include <cstdint>
#include <cstddef>

// ---------------------------------------------------------------------------
// Transformer block: LN1 -> MHA(16 heads, no mask) -> +res -> LN2 -> GELU MLP -> +res
// B=8 T=1024 D=1024 H=16 HD=64 FF=4096.  bf16 MFMA everywhere, fp32 accum.
// ---------------------------------------------------------------------------

typedef __bf16 bf16;
typedef __bf16 bf16x8 __attribute__((ext_vector_type(8)));
typedef __bf16 bf16x4 __attribute__((ext_vector_type(4)));
typedef float  f32x4  __attribute__((ext_vector_type(4)));
typedef uint32_t u32x4 __attribute__((ext_vector_type(4)));

#define BB    8
#define TT    1024
#define DD    1024
#define HH    16
#define HDIM  64
#define FFD   4096
#define MROWS (BB*TT)   // 8192

// async global->LDS, 16B per lane, LDS dest = wave-uniform base + lane*16
__device__ __forceinline__ void async_ld16(const void* g, void* l) {
  __builtin_amdgcn_global_load_lds(
      (const __attribute__((address_space(1))) uint32_t*)g,
      (__attribute__((address_space(3))) uint32_t*)l, 16, 0, 0);
}

// cheap GELU (tanh form, |err vs erf-form| <~1e-3, absorbed by bf16 out)
__device__ __forceinline__ float gelu_f(float v) {
  float z = 0.7978845608028654f * (v + 0.044715f * v * v * v);
  z = fminf(fmaxf(z, -9.0f), 9.0f);
  const float e = __expf(-2.0f * z);
  const float th = 1.0f - __fdividef(2.0f * e, 1.0f + e);
  return 0.5f * v * (1.0f + th);
}

// raw v_exp_f32: 2^x
__device__ __forceinline__ float exp2_fast(float x) {
  float r; asm("v_exp_f32 %0, %1" : "=v"(r) : "v"(x)); return r;
}
// packed f32->bf16 pair (no builtin on gfx950)
__device__ __forceinline__ uint32_t cvt_pk_bf16(float a, float b) {
  uint32_t r; asm("v_cvt_pk_bf16_f32 %0, %1, %2" : "=v"(r) : "v"(a), "v"(b));
  return r;
}

// ---------------------------------------------------------------------------
// merged Q/K/V per-head repack: z in [0,48): matrix = z/16, head = z%16.
// each (D, HD) head block -> rows of wtqkv (3072, 1024).
// ---------------------------------------------------------------------------
__global__ void k_transpose_qkv(const float* __restrict__ Wq, const float* __restrict__ Wk,
                                const float* __restrict__ Wv, bf16* __restrict__ dst) {
  __shared__ float tile[32][33];
  const int z = blockIdx.z;
  const int mm = z >> 4, hh = z & 15;
  const float* src = (mm == 0 ? Wq : mm == 1 ? Wk : Wv) + (size_t)hh * DD * HDIM;
  bf16* d = dst + ((size_t)mm * DD + (size_t)hh * HDIM) * DD;
  const int k0 = blockIdx.y * 32, n0 = blockIdx.x * 32;
  const int tx = threadIdx.x, ty = threadIdx.y; // (32,8)
#pragma unroll
  for (int i = 0; i < 4; ++i)
    tile[ty + i*8][tx] = src[(size_t)(k0 + ty + i*8) * HDIM + n0 + tx];
  __syncthreads();
#pragma unroll
  for (int i = 0; i < 4; ++i)
    d[(size_t)(n0 + ty + i*8) * DD + k0 + tx] = (bf16)tile[tx][ty + i*8];
}

// merged Wo/W1/W2 repack: 32x32 tiles, z-linear decode (1024 + 4096 + 4096 blocks)
__global__ void k_transpose_w3(const float* __restrict__ Wo, const float* __restrict__ W1,
                               const float* __restrict__ W2, bf16* __restrict__ wot,
                               bf16* __restrict__ w1t, bf16* __restrict__ w2t) {
  __shared__ float tile[32][33];
  const int z = blockIdx.x;
  const float* src; bf16* dst; int K, N, n0, k0;
  if (z < 1024)      { src = Wo; dst = wot; K = 1024; N = 1024;
                       n0 = (z & 31) * 32;        k0 = (z >> 5) * 32; }
  else if (z < 5120) { src = W1; dst = w1t; K = 1024; N = 4096; const int zz = z - 1024;
                       n0 = (zz & 127) * 32;      k0 = (zz >> 7) * 32; }
  else               { src = W2; dst = w2t; K = 4096; N = 1024; const int zz = z - 5120;
                       n0 = (zz & 31) * 32;       k0 = (zz >> 5) * 32; }
  const int tx = threadIdx.x, ty = threadIdx.y; // (32,8)
#pragma unroll
  for (int i = 0; i < 4; ++i)
    tile[ty + i*8][tx] = src[(size_t)(k0 + ty + i*8) * N + n0 + tx];
  __syncthreads();
#pragma unroll
  for (int i = 0; i < 4; ++i)
    dst[(size_t)(n0 + ty + i*8) * K + k0 + tx] = (bf16)tile[tx][ty + i*8];
}

__global__ void k_concat_bias(const float* __restrict__ bq, const float* __restrict__ bk,
                              const float* __restrict__ bv, float* __restrict__ out) {
  int i = blockIdx.x * 256 + threadIdx.x; // 3072
  float v = (i < 1024) ? bq[i] : (i < 2048) ? bk[i - 1024] : bv[i - 2048];
  out[i] = v;
}

// V part of qkv (B*T, 3072) -> vT[b][h][e][t]
__global__ void k_transpose_v(const bf16* __restrict__ qkv, bf16* __restrict__ vT) {
  __shared__ bf16 tile[32][33];
  const int bh = blockIdx.z;
  const int b = bh >> 4, h = bh & 15;
  const int t0 = blockIdx.x * 32, e0 = blockIdx.y * 32;
  const int tx = threadIdx.x, ty = threadIdx.y; // (32,8)
  const bf16* src = qkv + (size_t)b * TT * 3072 + 2048 + h * 64;
#pragma unroll
  for (int i = 0; i < 4; ++i)
    tile[ty + i*8][tx] = src[(size_t)(t0 + ty + i*8) * 3072 + e0 + tx];
  __syncthreads();
  bf16* dst = vT + ((size_t)bh * 64 + e0) * TT + t0;
#pragma unroll
  for (int i = 0; i < 4; ++i)
    dst[(size_t)(ty + i*8) * TT + tx] = tile[tx][ty + i*8];
}

// ---------------------------------------------------------------------------
// LayerNorm (f32 in -> bf16 out): one block per row, 256 threads
// ---------------------------------------------------------------------------
__global__ void k_layernorm(const float* __restrict__ x, const float* __restrict__ g,
                            const float* __restrict__ b, bf16* __restrict__ out) {
  const int row = blockIdx.x, tid = threadIdx.x;
  const float* xr = x + (size_t)row * DD;
  f32x4 v = *(const f32x4*)(xr + tid * 4);
  float s  = v[0] + v[1] + v[2] + v[3];
  float ss = v[0]*v[0] + v[1]*v[1] + v[2]*v[2] + v[3]*v[3];
#pragma unroll
  for (int m = 1; m < 64; m <<= 1) { s += __shfl_xor(s, m); ss += __shfl_xor(ss, m); }
  __shared__ float red[8];
  const int wid = tid >> 6;
  if ((tid & 63) == 0) { red[wid*2] = s; red[wid*2+1] = ss; }
  __syncthreads();
  s  = red[0] + red[2] + red[4] + red[6];
  ss = red[1] + red[3] + red[5] + red[7];
  const float mu = s * (1.0f / DD);
  const float var = ss * (1.0f / DD) - mu * mu;
  const float rs = rsqrtf(var + 1e-5f);
  bf16x4 o;
#pragma unroll
  for (int j = 0; j < 4; ++j)
    o[j] = (bf16)((v[j] - mu) * rs * g[tid*4 + j] + b[tid*4 + j]);
  *(bf16x4*)&out[(size_t)row * DD + tid * 4] = o;
}

// LayerNorm (bf16 in -> bf16 out): for the bf16 residual trunk x1
__global__ void k_layernorm_b(const bf16* __restrict__ x, const float* __restrict__ g,
                              const float* __restrict__ b, bf16* __restrict__ out) {
  const int row = blockIdx.x, tid = threadIdx.x;
  const bf16* xr = x + (size_t)row * DD;
  bf16x4 v4 = *(const bf16x4*)(xr + tid * 4);
  float v[4] = {(float)v4[0], (float)v4[1], (float)v4[2], (float)v4[3]};
  float s  = v[0] + v[1] + v[2] + v[3];
  float ss = v[0]*v[0] + v[1]*v[1] + v[2]*v[2] + v[3]*v[3];
#pragma unroll
  for (int m = 1; m < 64; m <<= 1) { s += __shfl_xor(s, m); ss += __shfl_xor(ss, m); }
  __shared__ float red[8];
  const int wid = tid >> 6;
  if ((tid & 63) == 0) { red[wid*2] = s; red[wid*2+1] = ss; }
  __syncthreads();
  s  = red[0] + red[2] + red[4] + red[6];
  ss = red[1] + red[3] + red[5] + red[7];
  const float mu = s * (1.0f / DD);
  const float var = ss * (1.0f / DD) - mu * mu;
  const float rs = rsqrtf(var + 1e-5f);
  bf16x4 o;
#pragma unroll
  for (int j = 0; j < 4; ++j)
    o[j] = (bf16)((v[j] - mu) * rs * g[tid*4 + j] + b[tid*4 + j]);
  *(bf16x4*)&out[(size_t)row * DD + tid * 4] = o;
}

// ---------------------------------------------------------------------------
// Shared helper macros for 256-tile 8-wave GEMMs
// ---------------------------------------------------------------------------
#define RD_B(reg, base) { _Pragma("unroll") \
    for (int nf = 0; nf < 4; ++nf) reg[nf] = *(const bf16x8*)((base) + nf*1024); }
#define RD_A4(reg, base, mb) { _Pragma("unroll") \
    for (int mf = 0; mf < 4; ++mf) reg[mf] = *(const bf16x8*)((base) + (mb+mf)*1024); }
#define MM(areg, breg, mb) { _Pragma("unroll") \
    for (int mf = 0; mf < 4; ++mf) _Pragma("unroll") \
      for (int nf = 0; nf < 4; ++nf) \
        acc[mb+mf][nf] = __builtin_amdgcn_mfma_f32_16x16x32_bf16(areg[mf], breg[nf], acc[mb+mf][nf], 0, 0, 0); }
#define SGA(off, lb) { async_ld16(aG0 + (off), (lb)+0*64);   async_ld16(aG1 + (off), (lb)+64*64); \
                       async_ld16(aG2 + (off), (lb)+128*64); async_ld16(aG3 + (off), (lb)+192*64); }
#define SGA_S0(off, lb) { async_ld16(aG0 + (off), (lb)+0*64);    async_ld16(aG2 + (off), (lb)+128*64); }
#define SGA_S1(off, lb) { async_ld16(aG1 + (off), (lb)+64*64);   async_ld16(aG3 + (off), (lb)+192*64); }
#define SGB_Q0(off, lb) { async_ld16(bG0 + (off), (lb)+0*64);    async_ld16(bG1 + (off), (lb)+64*64); }
#define SGB_Q1(off, lb) { async_ld16(bG2 + (off), (lb)+128*64);  async_ld16(bG3 + (off), (lb)+192*64); }
#define WAIT_LGKM { asm volatile("s_waitcnt lgkmcnt(0)" ::: "memory"); __builtin_amdgcn_sched_barrier(0); }
#define VMC(n)  { asm volatile("s_waitcnt vmcnt(" #n ")" ::: "memory"); __builtin_amdgcn_sched_barrier(0); }
#define BAR __builtin_amdgcn_s_barrier()
#define PR1 __builtin_amdgcn_s_setprio(1)
#define PR0 __builtin_amdgcn_s_setprio(0)

// ---------------------------------------------------------------------------
// k_gemm256n: 256x128 tile, 8 waves (4x2), BK=64, LDS 96 KB. QKV kernel
// (grid 768 = 3/CU exact). 2 phases/tile; full tile t+2 (6 loads) staged
// after last-reader barrier; boundary vmcnt(6). MODE 0: bf16 bias.
// ---------------------------------------------------------------------------
template<int MODE>
__global__ __launch_bounds__(512, 2)
void k_gemm256n(const bf16* __restrict__ A, const bf16* __restrict__ Bt,
                const float* __restrict__ bias, bf16* __restrict__ outb,
                int M, int N, int K) {
  __shared__ __align__(16) bf16 As[2][256 * 64];   // 64 KB
  __shared__ __align__(16) bf16 Bs[2][128 * 64];   // 32 KB
  const int tid = threadIdx.x;
  const int w = tid >> 6, l = tid & 63;
  const int wm = w >> 1, wn = w & 1;               // 4 x 2 waves
  const int l15 = l & 15, l4 = l >> 4;
  const int nbx = N >> 7;
  const int nwg = gridDim.x;
  const int cpx = nwg >> 3;
  const int swz = (blockIdx.x & 7) * cpx + (blockIdx.x >> 3);
  const int m0 = (swz / nbx) << 8, n0 = (swz % nbx) << 7;
  f32x4 acc[4][4] = {};
  const int l7 = l15 & 7;
  const int c0 = (l4 ^ l7) * 8;
  const int c1 = ((4 + l4) ^ l7) * 8;
  const bf16* const A00 = &As[0][(wm*64 + l15)*64 + c0];
  const bf16* const A01 = &As[0][(wm*64 + l15)*64 + c1];
  const bf16* const A10 = &As[1][(wm*64 + l15)*64 + c0];
  const bf16* const A11 = &As[1][(wm*64 + l15)*64 + c1];
  const bf16* const B00 = &Bs[0][(wn*64 + l15)*64 + c0];
  const bf16* const B01 = &Bs[0][(wn*64 + l15)*64 + c1];
  const bf16* const B10 = &Bs[1][(wn*64 + l15)*64 + c0];
  const bf16* const B11 = &Bs[1][(wn*64 + l15)*64 + c1];
  const int srow = l >> 3, sch = l & 7;
  const int schx = (sch ^ srow) * 8;
  const bf16* const aG0 = A  + (size_t)(m0 + w*8 + srow) * K + schx;
  const bf16* const aG1 = aG0 + (size_t)64 * K;
  const bf16* const aG2 = aG0 + (size_t)128 * K;
  const bf16* const aG3 = aG0 + (size_t)192 * K;
  const bf16* const bG0 = Bt + (size_t)(n0 + w*8 + srow) * K + schx;
  const bf16* const bG1 = bG0 + (size_t)64 * K;
  bf16* const LA0 = (bf16*)As[0] + w*512;
  bf16* const LA1 = (bf16*)As[1] + w*512;
  bf16* const LB0 = (bf16*)Bs[0] + w*512;
  bf16* const LB1 = (bf16*)Bs[1] + w*512;
  const int NT = K >> 6;   // even

#define SGB2(off, lb) { async_ld16(bG0 + (off), (lb)+0*64); async_ld16(bG1 + (off), (lb)+64*64); }

  SGA(0, LA0)  SGB2(0, LB0)
  SGA(64, LA1) SGB2(64, LB1)
  VMC(6);
  BAR;

  size_t ko = 0;
  for (int T = 0; T < NT; T += 2) {
    const bool nl  = (T + 2 < NT);
    const bool nl2 = (T + 3 < NT);
    bf16x8 b0[4], b1[4], a[4], a2[4];

    // ===== tile T (buf0) =====
    RD_B(b0, B00) RD_A4(a, A00, 0)
    BAR; WAIT_LGKM;
    PR1; MM(a, b0, 0) PR0;
    BAR;
    RD_B(b1, B01) RD_A4(a2, A01, 0)
    BAR; WAIT_LGKM;
    PR1; MM(a2, b1, 0) PR0;
    BAR;
    if (nl) { SGA(ko + 128, LA0) SGB2(ko + 128, LB0) }
    if (nl) { VMC(6); } else { VMC(0); }
    BAR;

    // ===== tile T+1 (buf1) =====
    RD_B(b0, B10) RD_A4(a, A10, 0)
    BAR; WAIT_LGKM;
    PR1; MM(a, b0, 0) PR0;
    BAR;
    RD_B(b1, B11) RD_A4(a2, A11, 0)
    BAR; WAIT_LGKM;
    PR1; MM(a2, b1, 0) PR0;
    BAR;
    if (nl2) { SGA(ko + 192, LA1) SGB2(ko + 192, LB1) }
    if (nl2) { VMC(6); } else { VMC(0); }
    BAR;

    ko += 128;
  }
#undef SGB2

#pragma unroll
  for (int mf = 0; mf < 4; ++mf) {
#pragma unroll
    for (int r = 0; r < 4; ++r) {
      const size_t grow = (size_t)(m0 + wm*64 + mf*16 + l4*4 + r);
      const size_t rowoff = grow * (size_t)N;
#pragma unroll
      for (int nf = 0; nf < 4; ++nf) {
        const int gcol = n0 + wn*64 + nf*16 + l15;
        float v = acc[mf][nf][r] + bias[gcol];
        if constexpr (MODE == 1) v = gelu_f(v);
        outb[rowoff + gcol] = (bf16)v;
      }
    }
  }
}

// ---------------------------------------------------------------------------
// k_gemm256p: 256x256 per-phase interleave (677 TF at FF1 shape). FF1 kernel.
// ---------------------------------------------------------------------------
template<int MODE>
__global__ __launch_bounds__(512, 2)
void k_gemm256p(const bf16* __restrict__ A, const bf16* __restrict__ Bt,
                const float* __restrict__ bias, bf16* __restrict__ outb,
                int M, int N, int K) {
  __shared__ __align__(16) bf16 As[2][256 * 64];
  __shared__ __align__(16) bf16 Bs[2][256 * 64];
  const int tid = threadIdx.x;
  const int w = tid >> 6, l = tid & 63;
  const int wm = w >> 2, wn = w & 3;
  const int l15 = l & 15, l4 = l >> 4;
  const int nbx = N >> 8;
  const int nwg = gridDim.x;
  const int cpx = nwg >> 3;
  const int swz = (blockIdx.x & 7) * cpx + (blockIdx.x >> 3);
  const int m0 = (swz / nbx) << 8, n0 = (swz % nbx) << 8;
  f32x4 acc[8][4] = {};
  const int l7 = l15 & 7;
  const int c0 = (l4 ^ l7) * 8;
  const int c1 = ((4 + l4) ^ l7) * 8;
  const bf16* const A00 = &As[0][(wm*128 + l15)*64 + c0];
  const bf16* const A01 = &As[0][(wm*128 + l15)*64 + c1];
  const bf16* const A10 = &As[1][(wm*128 + l15)*64 + c0];
  const bf16* const A11 = &As[1][(wm*128 + l15)*64 + c1];
  const bf16* const B00 = &Bs[0][(wn*64 + l15)*64 + c0];
  const bf16* const B01 = &Bs[0][(wn*64 + l15)*64 + c1];
  const bf16* const B10 = &Bs[1][(wn*64 + l15)*64 + c0];
  const bf16* const B11 = &Bs[1][(wn*64 + l15)*64 + c1];
  const int srow = l >> 3, sch = l & 7;
  const int schx = (sch ^ srow) * 8;
  const bf16* const aG0 = A  + (size_t)(m0 + w*8 + srow) * K + schx;
  const bf16* const aG1 = aG0 + (size_t)64 * K;
  const bf16* const aG2 = aG0 + (size_t)128 * K;
  const bf16* const aG3 = aG0 + (size_t)192 * K;
  const bf16* const bG0 = Bt + (size_t)(n0 + w*8 + srow) * K + schx;
  const bf16* const bG1 = bG0 + (size_t)64 * K;
  const bf16* const bG2 = bG0 + (size_t)128 * K;
  const bf16* const bG3 = bG0 + (size_t)192 * K;
  bf16* const LA0 = (bf16*)As[0] + w*512;
  bf16* const LA1 = (bf16*)As[1] + w*512;
  bf16* const LB0 = (bf16*)Bs[0] + w*512;
  bf16* const LB1 = (bf16*)Bs[1] + w*512;
  const int NT = K >> 6;

  SGA_S0(0, LA0) SGA_S1(0, LA0)
  SGB_Q0(0, LB0) SGB_Q1(0, LB0)
  SGA_S0(64, LA1)
  VMC(2);
  BAR;

  size_t ko = 0;
  for (int T = 0; T < NT; T += 2) {
    const bool s2 = (T + 2 < NT);
    const bool s3 = (T + 3 < NT);
    bf16x8 b0[4], b1[4], a[4];

    // ===== tile T (buf0) =====
    RD_B(b0, B00) RD_A4(a, A00, 0)
    SGA_S1(ko + 64, LA1)
    BAR; WAIT_LGKM;
    PR1; MM(a, b0, 0) PR0;
    BAR;
    RD_B(b1, B01) RD_A4(a, A01, 0)
    SGB_Q0(ko + 64, LB1)
    BAR; WAIT_LGKM;
    PR1; MM(a, b1, 0) PR0;
    BAR;
    RD_A4(a, A00, 4)
    SGB_Q1(ko + 64, LB1)
    BAR; WAIT_LGKM;
    PR1; MM(a, b0, 4) PR0;
    BAR;
    RD_A4(a, A01, 4)
    if (s2) SGA_S0(ko + 128, LA0)
    BAR; WAIT_LGKM;
    PR1; MM(a, b1, 4) PR0;
    if (s2) { VMC(2); } else { VMC(0); }
    BAR;

    // ===== tile T+1 (buf1) =====
    RD_B(b0, B10) RD_A4(a, A10, 0)
    if (s2) SGA_S1(ko + 128, LA0)
    BAR; WAIT_LGKM;
    PR1; MM(a, b0, 0) PR0;
    BAR;
    RD_B(b1, B11) RD_A4(a, A11, 0)
    if (s2) SGB_Q0(ko + 128, LB0)
    BAR; WAIT_LGKM;
    PR1; MM(a, b1, 0) PR0;
    BAR;
    RD_A4(a, A10, 4)
    if (s2) SGB_Q1(ko + 128, LB0)
    BAR; WAIT_LGKM;
    PR1; MM(a, b0, 4) PR0;
    BAR;
    RD_A4(a, A11, 4)
    if (s3) SGA_S0(ko + 192, LA1)
    BAR; WAIT_LGKM;
    PR1; MM(a, b1, 4) PR0;
    if (s3) { VMC(2); } else { VMC(0); }
    BAR;

    ko += 128;
  }

#pragma unroll
  for (int mf = 0; mf < 8; ++mf) {
#pragma unroll
    for (int r = 0; r < 4; ++r) {
      const size_t grow = (size_t)(m0 + wm*128 + mf*16 + l4*4 + r);
      const size_t rowoff = grow * (size_t)N;
#pragma unroll
      for (int nf = 0; nf < 4; ++nf) {
        const int gcol = n0 + wn*64 + nf*16 + l15;
        float v = acc[mf][nf][r] + bias[gcol];
        if constexpr (MODE == 1) v = gelu_f(v);
        outb[rowoff + gcol] = (bf16)v;
      }
    }
  }
}

// ---------------------------------------------------------------------------
// GEMM 128x128 (Wo, FF2).
// MODE 2: outb = bf16(acc + bias + resf)     (f32 residual, bf16 out — Wo)
// MODE 3: outf = acc + bias + float(resb)    (bf16 residual, f32 out — FF2)
// ---------------------------------------------------------------------------
template<int MODE>
__global__ __launch_bounds__(256)
void k_gemm(const bf16* __restrict__ A, const bf16* __restrict__ Bt,
            const float* __restrict__ bias, const float* __restrict__ resf,
            const bf16* __restrict__ resb,
            bf16* __restrict__ outb, float* __restrict__ outf,
            int M, int N, int K) {
  __shared__ __align__(16) bf16 As[128 * 64];
  __shared__ __align__(16) bf16 Bs[128 * 64];
  const int tid = threadIdx.x;
  const int w = tid >> 6, l = tid & 63;
  const int wm = w >> 1, wn = w & 1;
  const int l15 = l & 15, l4 = l >> 4;
  const int m0 = blockIdx.y * 128, n0 = blockIdx.x * 128;

  f32x4 acc[4][4] = {};

  const int l7 = l15 & 7;
  const int c0 = (l4 ^ l7) * 8, c1 = ((4 + l4) ^ l7) * 8;
  const bf16* const Ab = &As[(wm*64 + l15)*64];
  const bf16* const Bb = &Bs[(wn*64 + l15)*64];

  const int sr8 = l >> 3, sl7 = l & 7;
  const int schx = (sl7 ^ sr8) * 8;
  const bf16* const gA0 = A  + (size_t)(m0 + w*32 + sr8) * K + schx;
  const bf16* const gA1 = gA0 + (size_t)8 * K;
  const bf16* const gA2 = gA0 + (size_t)16 * K;
  const bf16* const gA3 = gA0 + (size_t)24 * K;
  const bf16* const gB0 = Bt + (size_t)(n0 + w*32 + sr8) * K + schx;
  const bf16* const gB1 = gB0 + (size_t)8 * K;
  const bf16* const gB2 = gB0 + (size_t)16 * K;
  const bf16* const gB3 = gB0 + (size_t)24 * K;
  bf16* const lA = (bf16*)As + w*32*64;
  bf16* const lB = (bf16*)Bs + w*32*64;

  for (int k0 = 0; k0 < K; k0 += 64) {
    async_ld16(gA0 + k0, lA);          async_ld16(gA1 + k0, lA + 8*64);
    async_ld16(gA2 + k0, lA + 16*64);  async_ld16(gA3 + k0, lA + 24*64);
    async_ld16(gB0 + k0, lB);          async_ld16(gB1 + k0, lB + 8*64);
    async_ld16(gB2 + k0, lB + 16*64);  async_ld16(gB3 + k0, lB + 24*64);
    __syncthreads();
#pragma unroll
    for (int kk = 0; kk < 2; ++kk) {
      const int cc = kk ? c1 : c0;
      bf16x8 af[4], bfr[4];
#pragma unroll
      for (int mf = 0; mf < 4; ++mf) af[mf] = *(const bf16x8*)(Ab + mf*1024 + cc);
#pragma unroll
      for (int nf = 0; nf < 4; ++nf) bfr[nf] = *(const bf16x8*)(Bb + nf*1024 + cc);
#pragma unroll
      for (int mf = 0; mf < 4; ++mf)
#pragma unroll
        for (int nf = 0; nf < 4; ++nf)
          acc[mf][nf] = __builtin_amdgcn_mfma_f32_16x16x32_bf16(af[mf], bfr[nf], acc[mf][nf], 0, 0, 0);
    }
    __syncthreads();
  }

#pragma unroll
  for (int mf = 0; mf < 4; ++mf) {
#pragma unroll
    for (int r = 0; r < 4; ++r) {
      const size_t grow = (size_t)(m0 + wm*64 + mf*16 + l4*4 + r);
      const size_t rowoff = grow * (size_t)N;
#pragma unroll
      for (int nf = 0; nf < 4; ++nf) {
        const int gcol = n0 + wn*64 + nf*16 + l15;
        float v = acc[mf][nf][r] + bias[gcol];
        if constexpr (MODE == 1) v = gelu_f(v);
        if constexpr (MODE == 2) {
          v += resf[rowoff + gcol];
          outb[rowoff + gcol] = (bf16)v;
        } else if constexpr (MODE == 3) {
          v += (float)resb[rowoff + gcol];
          outf[rowoff + gcol] = v;
        } else {
          outb[rowoff + gcol] = (bf16)v;
        }
      }
    }
  }
}

// ---------------------------------------------------------------------------
// Flash attention v4 (R7, unchanged): swapped QK^T (lane owns q=l15),
// in-register P via cvt_pk + ds_bpermute; 512 thr = 8 waves x 16 q-rows;
// KV tiles 64, dbuf swizzled LDS (32 KB); XCD-chunked grid; defer-max.
// ---------------------------------------------------------------------------
__global__ __launch_bounds__(512)
void k_attn(const bf16* __restrict__ qkv, const bf16* __restrict__ vT,
            bf16* __restrict__ ctx) {
  const int tid = threadIdx.x;
  const int w = tid >> 6, l = tid & 63;
  const int l15 = l & 15, l4 = l >> 4;

  const int gid = ((int)blockIdx.x & 7) * 128 + ((int)blockIdx.x >> 3);
  const int qt = gid & 7;
  const int bh = gid >> 3;
  const int h = bh & 15, b = bh >> 4;

  __shared__ __align__(16) bf16 Ks[2][64 * 64];
  __shared__ __align__(16) bf16 Vs[2][64 * 64];

  const bf16* base = qkv + (size_t)b * TT * 3072;
  const bf16* Qp = base + h * 64;
  const bf16* Kp = base + 1024 + h * 64;
  const bf16* Vtp = vT + (size_t)bh * HDIM * TT;

  const float SCL = 0.125f * 1.44269504f;
  const float THR = 8.0f * 1.44269504f;

  const int qrow = qt * 128 + w * 16 + l15;
  bf16x8 qf[2];
  {
    bf16x8 q0 = *(const bf16x8*)&Qp[(size_t)qrow * 3072 + l4 * 8];
    bf16x8 q1 = *(const bf16x8*)&Qp[(size_t)qrow * 3072 + 32 + l4 * 8];
#pragma unroll
    for (int j = 0; j < 8; ++j) {
      qf[0][j] = (bf16)((float)q0[j] * SCL);
      qf[1][j] = (bf16)((float)q1[j] * SCL);
    }
  }

  f32x4 oacc[4] = {};
  float mrow = -1e30f;
  float lrow = 0.f;

  const int l7 = l15 & 7;
  const int c0 = (l4 ^ l7) * 8, c1 = ((4 + l4) ^ l7) * 8;

  const int aL0 = (((l4 & 1) << 5) + l15) << 2;
  const int aL1 = aL0 + 64;
  const bool hi = (l & 32) != 0;

  const int srow = w * 8 + (l >> 3);
  const int sch = (l & 7) ^ (srow & 7);

  auto stage = [&](int buf, int t) {
    const int kv0 = t * 64;
    async_ld16(Kp + (size_t)(kv0 + srow) * 3072 + sch * 8, &Ks[buf][w * 512]);
    async_ld16(Vtp + (size_t)srow * TT + kv0 + sch * 8, &Vs[buf][w * 512]);
  };

  stage(0, 0);
  for (int t = 0; t < TT / 64; ++t) {
    const int cur = t & 1;
    __syncthreads();
    if (t + 1 < TT / 64) stage(cur ^ 1, t + 1);

    const bf16* const Kc = &Ks[cur][l15 * 64];
    const bf16* const Vc = &Vs[cur][l15 * 64];

    f32x4 sacc[4] = {};
    __builtin_amdgcn_s_setprio(1);
#pragma unroll
    for (int nf = 0; nf < 4; ++nf) {
      bf16x8 k0 = *(const bf16x8*)(Kc + nf*1024 + c0);
      bf16x8 k1 = *(const bf16x8*)(Kc + nf*1024 + c1);
      sacc[nf] = __builtin_amdgcn_mfma_f32_16x16x32_bf16(k0, qf[0], sacc[nf], 0, 0, 0);
      sacc[nf] = __builtin_amdgcn_mfma_f32_16x16x32_bf16(k1, qf[1], sacc[nf], 0, 0, 0);
    }
    __builtin_amdgcn_s_setprio(0);

    float m = fmaxf(fmaxf(sacc[0][0], sacc[0][1]), fmaxf(sacc[0][2], sacc[0][3]));
#pragma unroll
    for (int nf = 1; nf < 4; ++nf)
      m = fmaxf(m, fmaxf(fmaxf(sacc[nf][0], sacc[nf][1]), fmaxf(sacc[nf][2], sacc[nf][3])));
    m = fmaxf(m, __shfl_xor(m, 16));
    m = fmaxf(m, __shfl_xor(m, 32));

    const int ok = (m <= mrow + THR);
    if (!__all(ok)) {
      const float mn = fmaxf(mrow, m);
      const float e = exp2_fast(mrow - mn);
      mrow = mn;
      lrow *= e;
      const int qb = l4 << 2;
      float e0 = __shfl(e, qb + 0), e1 = __shfl(e, qb + 1);
      float e2 = __shfl(e, qb + 2), e3 = __shfl(e, qb + 3);
#pragma unroll
      for (int nf = 0; nf < 4; ++nf) {
        oacc[nf][0] *= e0; oacc[nf][1] *= e1;
        oacc[nf][2] *= e2; oacc[nf][3] *= e3;
      }
    }

    float p[4][4];
    float ls = 0.f;
    uint32_t pk0[4], pk1[4];
#pragma unroll
    for (int nf = 0; nf < 4; ++nf) {
#pragma unroll
      for (int r = 0; r < 4; ++r) {
        p[nf][r] = exp2_fast(sacc[nf][r] - mrow);
        ls += p[nf][r];
      }
      pk0[nf] = cvt_pk_bf16(p[nf][0], p[nf][1]);
      pk1[nf] = cvt_pk_bf16(p[nf][2], p[nf][3]);
    }
    ls += __shfl_xor(ls, 16);
    ls += __shfl_xor(ls, 32);
    lrow += ls;

    __builtin_amdgcn_s_setprio(1);
#pragma unroll
    for (int kk = 0; kk < 2; ++kk) {
      const int nfa = 2*kk, nfb = 2*kk + 1;
      int u0 = __builtin_amdgcn_ds_bpermute(aL0, (int)pk0[nfa]);
      int u1 = __builtin_amdgcn_ds_bpermute(aL0, (int)pk0[nfb]);
      int v0 = __builtin_amdgcn_ds_bpermute(aL0, (int)pk1[nfa]);
      int v1 = __builtin_amdgcn_ds_bpermute(aL0, (int)pk1[nfb]);
      int x0 = __builtin_amdgcn_ds_bpermute(aL1, (int)pk0[nfa]);
      int x1 = __builtin_amdgcn_ds_bpermute(aL1, (int)pk0[nfb]);
      int y0 = __builtin_amdgcn_ds_bpermute(aL1, (int)pk1[nfa]);
      int y1 = __builtin_amdgcn_ds_bpermute(aL1, (int)pk1[nfb]);
      u32x4 pw;
      pw[0] = (uint32_t)(hi ? u1 : u0);
      pw[1] = (uint32_t)(hi ? v1 : v0);
      pw[2] = (uint32_t)(hi ? x1 : x0);
      pw[3] = (uint32_t)(hi ? y1 : y0);
      bf16x8 pa = __builtin_bit_cast(bf16x8, pw);
      const int cc = kk ? c1 : c0;
#pragma unroll
      for (int nf = 0; nf < 4; ++nf) {
        bf16x8 vb = *(const bf16x8*)(Vc + nf*1024 + cc);
        oacc[nf] = __builtin_amdgcn_mfma_f32_16x16x32_bf16(pa, vb, oacc[nf], 0, 0, 0);
      }
    }
    __builtin_amdgcn_s_setprio(0);
  }

  const int qb = l4 << 2;
  float li0 = 1.0f / __shfl(lrow, qb + 0);
  float li1 = 1.0f / __shfl(lrow, qb + 1);
  float li2 = 1.0f / __shfl(lrow, qb + 2);
  float li3 = 1.0f / __shfl(lrow, qb + 3);
  bf16* outp = ctx + ((size_t)b * TT + qt * 128 + w * 16) * DD + h * 64;
#pragma unroll
  for (int nf = 0; nf < 4; ++nf) {
    outp[(size_t)(qb + 0) * DD + l15 + nf*16] = (bf16)(oacc[nf][0] * li0);
    outp[(size_t)(qb + 1) * DD + l15 + nf*16] = (bf16)(oacc[nf][1] * li1);
    outp[(size_t)(qb + 2) * DD + l15 + nf*16] = (bf16)(oacc[nf][2] * li2);
    outp[(size_t)(qb + 3) * DD + l15 + nf*16] = (bf16)(oacc[nf][3] * li3);
  }
}

// ---------------------------------------------------------------------------
// launch
// ---------------------------------------------------------------------------
extern "C" void kernel_launch(void* const* d_in, const int* in_sizes, int n_in,
                              void* d_out, int out_size, void* d_ws, size_t ws_size,
                              hipStream_t stream) {
  const float* x     = (const float*)d_in[0];
  const float* ln1_g = (const float*)d_in[1];
  const float* ln1_b = (const float*)d_in[2];
  const float* ln2_g = (const float*)d_in[3];
  const float* ln2_b = (const float*)d_in[4];
  const float* Wq    = (const float*)d_in[5];
  const float* bq    = (const float*)d_in[6];
  const float* Wk    = (const float*)d_in[7];
  const float* bk    = (const float*)d_in[8];
  const float* Wv    = (const float*)d_in[9];
  const float* bv    = (const float*)d_in[10];
  const float* Wo    = (const float*)d_in[11];
  const float* bo    = (const float*)d_in[12];
  const float* W1    = (const float*)d_in[13];
  const float* b1    = (const float*)d_in[14];
  const float* W2    = (const float*)d_in[15];
  const float* b2    = (const float*)d_in[16];
  float* out = (float*)d_out;

  char* ws = (char*)d_ws;
  bf16* h1    = (bf16*)(ws + 0);                    // 16MB (dead after QKV GEMM)
  bf16* vT    = (bf16*)(ws + 0);                    // aliases h1
  bf16* qkv   = (bf16*)(ws + 16777216);             // 48MB
  bf16* ctx   = (bf16*)(ws + 67108864);             // 16MB
  bf16* u     = (bf16*)(ws + 16777216);             // 64MB, aliases qkv+ctx (dead)
  bf16* x1b   = (bf16*)(ws + 83886080);             // 16MB (bf16 residual trunk)
  bf16* wtqkv = (bf16*)(ws + 117440512);            // 6MB
  bf16* wot   = (bf16*)(ws + 123731968);            // 2MB
  bf16* w1t   = (bf16*)(ws + 125829120);            // 8MB
  bf16* w2t   = (bf16*)(ws + 134217728);            // 8MB
  float* bqkv = (float*)(ws + 142606336);           // 12KB
  bf16* h2 = h1;

  dim3 tb(32, 8);
  // merged repacks: Q/K/V heads (1 launch), Wo+W1+W2 (1 launch)
  k_transpose_qkv<<<dim3(2, 32, 48), tb, 0, stream>>>(Wq, Wk, Wv, wtqkv);
  k_transpose_w3<<<dim3(9216), tb, 0, stream>>>(Wo, W1, W2, wot, w1t, w2t);
  k_concat_bias<<<dim3(12), 256, 0, stream>>>(bq, bk, bv, bqkv);

  k_layernorm<<<dim3(MROWS), 256, 0, stream>>>(x, ln1_g, ln1_b, h1);

  // QKV: (8192,1024) x (3072,1024)^T -> qkv bf16  [gemm256n, grid 768 = 3/CU]
  k_gemm256n<0><<<dim3((MROWS/256)*(3072/128)), 512, 0, stream>>>(
      h1, wtqkv, bqkv, qkv, MROWS, 3072, DD);

  k_transpose_v<<<dim3(32, 2, 128), tb, 0, stream>>>(qkv, vT);

  k_attn<<<dim3(1024), 512, 0, stream>>>(qkv, vT, ctx);

  // Wo + residual: x1b = bf16(x + ctx@Wo + bo)   [bf16 trunk: halves traffic]
  k_gemm<2><<<dim3(8, 64), 256, 0, stream>>>(ctx, wot, bo, x, nullptr,
                                             x1b, nullptr, MROWS, DD, DD);

  k_layernorm_b<<<dim3(MROWS), 256, 0, stream>>>(x1b, ln2_g, ln2_b, h2);

  // FF1 + GELU -> u bf16   [gemm256p]
  k_gemm256p<1><<<dim3((MROWS/256)*(FFD/256)), 512, 0, stream>>>(
      h2, w1t, b1, u, MROWS, FFD, DD);

  // FF2 + residual -> out f32  (bf16 residual read)
  k_gemm<3><<<dim3(8, 64), 256, 0, stream>>>(u, w2t, b2, nullptr, x1b,
                                             nullptr, out, MROWS, DD, FFD);

  (void)in_sizes; (void)n_in; (void)out_size; (void)ws_size;
}